// Round 13
// baseline (154.705 us; speedup 1.0000x reference)
//
#include <hip/hip_runtime.h>

#define D 128

typedef __attribute__((ext_vector_type(8))) short bf16x8;
typedef __attribute__((ext_vector_type(4))) float f32x4;
typedef __attribute__((ext_vector_type(4))) unsigned u32x4;

__device__ inline unsigned short f2bf(float f) {  // RNE fp32->bf16
    unsigned u = __builtin_bit_cast(unsigned, f);
    u += 0x7FFFu + ((u >> 16) & 1u);
    return (unsigned short)(u >> 16);
}
__device__ inline float bf_lo(unsigned u) { return __builtin_bit_cast(float, u << 16); }
__device__ inline float bf_hi(unsigned u) { return __builtin_bit_cast(float, u & 0xFFFF0000u); }

// ---------------- W pre-pack (both layers) + counts zero, one launch ----------------
__global__ __launch_bounds__(256) void k_pack_zero(const float* __restrict__ W1,
                                                   const float* __restrict__ W2,
                                                   unsigned short* __restrict__ wp,
                                                   int* __restrict__ counts, int n) {
    if (blockIdx.x < 16) {
        const int t = blockIdx.x * 256 + threadIdx.x;  // 0..4095
        const float* W = (t < 2048) ? W1 : W2;
        const int tt = t & 2047;
        const int lane = tt & 63;
        const int frag = tt >> 6;  // 0..31
        const int ct = frag >> 2;
        const int kk = frag & 3;
        const int col16 = lane & 15;
        const int kgrp = lane >> 4;
        bf16x8 d;
#pragma unroll
        for (int e = 0; e < 8; ++e)
            d[e] = (short)f2bf(W[(kk * 32 + kgrp * 8 + e) * D + ct * 16 + col16]);
        *reinterpret_cast<bf16x8*>(wp + (size_t)t * 8) = d;
    } else {
        const int i = (blockIdx.x - 16) * 256 + threadIdx.x;
        if (i < n) counts[i] = 0;
    }
}

// Histogram that also records each edge's rank within its dst segment.
__global__ void k_hist_rank(const int* __restrict__ dst, int* __restrict__ counts,
                            int* __restrict__ rank, int nE) {
    int e4 = (blockIdx.x * blockDim.x + threadIdx.x) * 4;
    if (e4 + 4 <= nE) {
        const int4 d = *reinterpret_cast<const int4*>(dst + e4);
        int4 r;
        r.x = atomicAdd(&counts[d.x], 1);
        r.y = atomicAdd(&counts[d.y], 1);
        r.z = atomicAdd(&counts[d.z], 1);
        r.w = atomicAdd(&counts[d.w], 1);
        *reinterpret_cast<int4*>(rank + e4) = r;
    } else {
        for (int e = e4; e < nE; ++e) rank[e] = atomicAdd(&counts[dst[e]], 1);
    }
}

// Pass 1: per-block (1024-element tile) sums; fused dis = rsqrt(counts+1).
__global__ __launch_bounds__(256) void k_scan_part(const int* __restrict__ counts,
                                                   int* __restrict__ bsum,
                                                   float* __restrict__ dis, int n) {
    const int t = threadIdx.x;
    const int base = blockIdx.x * 1024 + t * 4;
    int4 c = make_int4(0, 0, 0, 0);
    if (base + 4 <= n) {
        c = *reinterpret_cast<const int4*>(counts + base);
        float4 dv;
        dv.x = rsqrtf((float)(c.x + 1));
        dv.y = rsqrtf((float)(c.y + 1));
        dv.z = rsqrtf((float)(c.z + 1));
        dv.w = rsqrtf((float)(c.w + 1));
        *reinterpret_cast<float4*>(dis + base) = dv;
    } else if (base < n) {
        int cc[4] = {0, 0, 0, 0};
        for (int k = 0; k < 4; ++k)
            if (base + k < n) {
                cc[k] = counts[base + k];
                dis[base + k] = rsqrtf((float)(cc[k] + 1));
            }
        c.x = cc[0]; c.y = cc[1]; c.z = cc[2]; c.w = cc[3];
    }
    __shared__ int red[256];
    red[t] = c.x + c.y + c.z + c.w;
    __syncthreads();
    for (int off = 128; off > 0; off >>= 1) {
        if (t < off) red[t] += red[t + off];
        __syncthreads();
    }
    if (t == 0) bsum[blockIdx.x] = red[0];
}

// Pass 2: scan block sums in LDS, local-scan tile, write starts.
__global__ __launch_bounds__(256) void k_scan_final(const int* __restrict__ counts,
                                                    const int* __restrict__ bsum,
                                                    int* __restrict__ starts, int n, int nB) {
    __shared__ int sb[128];
    __shared__ int ts[256];
    const int t = threadIdx.x;
    const int b = blockIdx.x;

    if (t < 128) sb[t] = (t < nB) ? bsum[t] : 0;
    __syncthreads();
    for (int off = 1; off < 128; off <<= 1) {
        int add = (t < 128 && t >= off) ? sb[t - off] : 0;
        __syncthreads();
        if (t < 128) sb[t] += add;
        __syncthreads();
    }
    const int block_off = (b > 0) ? sb[b - 1] : 0;

    const int base = b * 1024 + t * 4;
    int4 c = make_int4(0, 0, 0, 0);
    if (base + 4 <= n) {
        c = *reinterpret_cast<const int4*>(counts + base);
    } else if (base < n) {
        if (base + 0 < n) c.x = counts[base + 0];
        if (base + 1 < n) c.y = counts[base + 1];
        if (base + 2 < n) c.z = counts[base + 2];
    }
    const int s = c.x + c.y + c.z + c.w;
    ts[t] = s;
    __syncthreads();
    for (int off = 1; off < 256; off <<= 1) {
        int add = (t >= off) ? ts[t - off] : 0;
        __syncthreads();
        ts[t] += add;
        __syncthreads();
    }
    int excl = block_off + ts[t] - s;

    int4 w;
    w.x = excl;
    w.y = w.x + c.x;
    w.z = w.y + c.y;
    w.w = w.z + c.z;
    if (base + 4 <= n) {
        *reinterpret_cast<int4*>(starts + base) = w;
    } else if (base < n) {
        if (base + 0 < n) starts[base + 0] = w.x;
        if (base + 1 < n) starts[base + 1] = w.y;
        if (base + 2 < n) starts[base + 2] = w.z;
    }
    if (b == 0 && t == 0) starts[n] = sb[nB - 1];  // = nE
}

// ---------------- FUSED scatter + layer-1 GEMM (independent work, one launch) ----
__global__ __launch_bounds__(256, 3) void k_scatter_gemm(const int* __restrict__ src,
                                                         const int* __restrict__ dst,
                                                         const int* __restrict__ rank,
                                                         const int* __restrict__ starts,
                                                         int* __restrict__ esrc, int nE, int nsc,
                                                         const float* __restrict__ X,
                                                         const unsigned short* __restrict__ wp,
                                                         const float* __restrict__ dis,
                                                         unsigned short* __restrict__ outbf,
                                                         int n) {
    __shared__ __align__(16) unsigned short At[64 * 128];  // 16KB, swizzled
    if (blockIdx.x < nsc) {
        // ---------- scatter role ----------
        int e4 = (blockIdx.x * blockDim.x + threadIdx.x) * 4;
        if (e4 + 4 <= nE) {
            const int4 s = *reinterpret_cast<const int4*>(src + e4);
            const int4 d = *reinterpret_cast<const int4*>(dst + e4);
            const int4 r = *reinterpret_cast<const int4*>(rank + e4);
            esrc[starts[d.x] + r.x] = s.x;
            esrc[starts[d.y] + r.y] = s.y;
            esrc[starts[d.z] + r.z] = s.z;
            esrc[starts[d.w] + r.w] = s.w;
        } else {
            for (int e = e4; e < nE; ++e)
                esrc[starts[dst[e]] + rank[e]] = src[e];
        }
        return;
    }
    // ---------- GEMM role ----------
    const int st = blockIdx.x - nsc;
    const int tid = threadIdx.x;
    const int lane = tid & 63;
    const int wv = tid >> 6;
    const int col16 = lane & 15;
    const int kgrp = lane >> 4;

    float4 pf[8];
#pragma unroll
    for (int c = 0; c < 4; ++c) {
        const int idx = c * 2048 + tid * 8;
        const int row = idx >> 7;
        const int col = idx & 127;
        int grow = st * 64 + row;
        if (grow >= n) grow = n - 1;
        const float4* p = reinterpret_cast<const float4*>(X + (size_t)grow * D + col);
        pf[2 * c] = p[0];
        pf[2 * c + 1] = p[1];
    }
#pragma unroll
    for (int c = 0; c < 4; ++c) {
        const int idx = c * 2048 + tid * 8;
        const int row = idx >> 7;
        const int col = idx & 127;
        const float4 f0 = pf[2 * c], f1 = pf[2 * c + 1];
        float v[8] = {f0.x, f0.y, f0.z, f0.w, f1.x, f1.y, f1.z, f1.w};
        bf16x8 d;
#pragma unroll
        for (int e = 0; e < 8; ++e) d[e] = (short)f2bf(v[e]);
        const int waddr = row * 128 + (col ^ ((row & 7) << 3));
        *reinterpret_cast<bf16x8*>(&At[waddr]) = d;
    }
    __syncthreads();

    bf16x8 a[4];
#pragma unroll
    for (int kk = 0; kk < 4; ++kk) {
        const int raddr = (wv * 16 + col16) * 128 +
                          ((kk * 32 + kgrp * 8) ^ ((col16 & 7) << 3));
        a[kk] = *reinterpret_cast<const bf16x8*>(&At[raddr]);
    }

    const int node = st * 64 + wv * 16 + col16;
    const float dn = (node < n) ? dis[node] : 0.0f;
    unsigned short* op = outbf + (size_t)node * D + kgrp * 4;

#pragma unroll
    for (int h = 0; h < 2; ++h) {
        bf16x8 bw[4][4];
#pragma unroll
        for (int c2 = 0; c2 < 4; ++c2)
#pragma unroll
            for (int kk = 0; kk < 4; ++kk)
                bw[c2][kk] = *reinterpret_cast<const bf16x8*>(
                        wp + (size_t)(((h * 4 + c2) * 4 + kk) * 64 + lane) * 8);

        f32x4 acc[4];
#pragma unroll
        for (int c2 = 0; c2 < 4; ++c2) acc[c2] = (f32x4){0.f, 0.f, 0.f, 0.f};
#pragma unroll
        for (int kk = 0; kk < 4; ++kk)
#pragma unroll
            for (int c2 = 0; c2 < 4; ++c2)  // SWAPPED operands: D = (X@W)^T
                acc[c2] = __builtin_amdgcn_mfma_f32_16x16x32_bf16(bw[c2][kk], a[kk], acc[c2], 0, 0, 0);

        if (node < n) {
#pragma unroll
            for (int c2 = 0; c2 < 4; ++c2) {
                uint2 w;
                w.x = (unsigned)f2bf(dn * acc[c2][0]) | ((unsigned)f2bf(dn * acc[c2][1]) << 16);
                w.y = (unsigned)f2bf(dn * acc[c2][2]) | ((unsigned)f2bf(dn * acc[c2][3]) << 16);
                *reinterpret_cast<uint2*>(op + (h * 4 + c2) * 16) = w;
            }
        }
    }
}

// ---------------- gather chunk core: 8-deep pipelined row accumulate ----------------
__device__ __forceinline__ void accum_chunk(const unsigned short* __restrict__ hs,
                                            int myedge, int cnt, int grp, int sub,
                                            float acc[8]) {
    auto row16 = [&](int s) -> u32x4 {
        return *reinterpret_cast<const u32x4*>(hs + (size_t)s * D + sub * 8);
    };
    for (int k = 0; k < cnt; k += 8) {
        u32x4 u[8];
#pragma unroll
        for (int q = 0; q < 8; ++q) {
            const int tq = min(k + q, cnt - 1);  // clamp: dupes hit L1
            const int s = __shfl(myedge, (grp << 4) | tq);
            u[q] = row16(s);
        }
        const int rem = cnt - k;
#pragma unroll
        for (int q = 0; q < 8; ++q) {
            if (q < rem) {
#pragma unroll
                for (int e = 0; e < 4; ++e) {
                    acc[2 * e] += bf_lo(u[q][e]);
                    acc[2 * e + 1] += bf_hi(u[q][e]);
                }
            }
        }
    }
}

// ---------------- FUSED gather + GEMM (layer 1 agg + layer 2 matmul) ----------------
// R12: back to R10's lean quad-serial body (52 VGPR) but at __launch_bounds__(256,6):
// 6 blocks/CU co-resident (96KB LDS, VGPR cap ~85) -> the whole 1563-block grid is
// resident at once, 24 waves/CU of gather streams. Occupancy, not ILP, is the lever.
__global__ __launch_bounds__(256, 6) void k_gather_gemm(const unsigned short* __restrict__ hs,
                                                        const int* __restrict__ starts,
                                                        const int* __restrict__ esrc,
                                                        const float* __restrict__ dis,
                                                        const float* __restrict__ bias,
                                                        const unsigned short* __restrict__ wp,
                                                        unsigned short* __restrict__ outbf,
                                                        int n) {
    __shared__ __align__(16) unsigned short At[64 * 128];  // 16KB, swizzled
    const int tid = threadIdx.x;
    const int lane = tid & 63;
    const int wv = tid >> 6;
    const int col16 = lane & 15;
    const int kgrp = lane >> 4;
    const int grp = lane >> 4;   // node within 4-node quad
    const int sub = lane & 15;   // lane within node
    const int st = blockIdx.x;

    const float4 bv0 = reinterpret_cast<const float4*>(bias)[sub * 2 + 0];
    const float4 bv1 = reinterpret_cast<const float4*>(bias)[sub * 2 + 1];

    // ---- metadata for all 4 quads: independent loads, all in flight together ----
    int ic[4], beg[4], end[4], cnt0[4], my[4];
    float di[4];
    u32x4 selfrow[4];
#pragma unroll
    for (int p = 0; p < 4; ++p) {
        const int i = st * 64 + wv * 16 + p * 4 + grp;
        ic[p] = (i < n) ? i : (n - 1);
    }
#pragma unroll
    for (int p = 0; p < 4; ++p) {
        beg[p] = starts[ic[p]];
        end[p] = starts[ic[p] + 1];
        di[p] = dis[ic[p]];
        selfrow[p] = *reinterpret_cast<const u32x4*>(hs + (size_t)ic[p] * D + sub * 8);
    }
#pragma unroll
    for (int p = 0; p < 4; ++p) {
        cnt0[p] = min(end[p] - beg[p], 16);
        my[p] = (sub < cnt0[p]) ? esrc[beg[p] + sub] : 0;
    }

    // ---- accumulate per quad (metadata already in flight) ----
#pragma unroll
    for (int p = 0; p < 4; ++p) {
        float acc[8];
#pragma unroll
        for (int e = 0; e < 4; ++e) {
            acc[2 * e] = bf_lo(selfrow[p][e]);
            acc[2 * e + 1] = bf_hi(selfrow[p][e]);
        }
        if (cnt0[p] > 0) accum_chunk(hs, my[p], cnt0[p], grp, sub, acc);
        // rare chunks beyond 16 edges
        for (int j = beg[p] + 16; j < end[p]; j += 16) {
            const int cnt = min(end[p] - j, 16);
            const int me = (sub < cnt) ? esrc[j + sub] : 0;
            accum_chunk(hs, me, cnt, grp, sub, acc);
        }

        float o[8];
        o[0] = di[p] * acc[0] + bv0.x; o[1] = di[p] * acc[1] + bv0.y;
        o[2] = di[p] * acc[2] + bv0.z; o[3] = di[p] * acc[3] + bv0.w;
        o[4] = di[p] * acc[4] + bv1.x; o[5] = di[p] * acc[5] + bv1.y;
        o[6] = di[p] * acc[6] + bv1.z; o[7] = di[p] * acc[7] + bv1.w;

        u32x4 w;  // ReLU + bf16 pack
#pragma unroll
        for (int e = 0; e < 4; ++e)
            w[e] = (unsigned)f2bf(fmaxf(o[2 * e], 0.0f)) |
                   ((unsigned)f2bf(fmaxf(o[2 * e + 1], 0.0f)) << 16);
        const int lrow = wv * 16 + p * 4 + grp;
        const int waddr = lrow * 128 + ((sub * 8) ^ ((lrow & 7) << 3));
        *reinterpret_cast<u32x4*>(&At[waddr]) = w;
    }
    __syncthreads();

    // ---- GEMM phase ----
    bf16x8 a[4];
#pragma unroll
    for (int kk = 0; kk < 4; ++kk) {
        const int raddr = (wv * 16 + col16) * 128 +
                          ((kk * 32 + kgrp * 8) ^ ((col16 & 7) << 3));
        a[kk] = *reinterpret_cast<const bf16x8*>(&At[raddr]);
    }

    const int node = st * 64 + wv * 16 + col16;
    const float dn = (node < n) ? dis[node] : 0.0f;
    unsigned short* op = outbf + (size_t)node * D + kgrp * 4;

#pragma unroll
    for (int h = 0; h < 2; ++h) {
        bf16x8 bw[4][4];
#pragma unroll
        for (int c2 = 0; c2 < 4; ++c2)
#pragma unroll
            for (int kk = 0; kk < 4; ++kk)
                bw[c2][kk] = *reinterpret_cast<const bf16x8*>(
                        wp + (size_t)(((h * 4 + c2) * 4 + kk) * 64 + lane) * 8);

        f32x4 acc2[4];
#pragma unroll
        for (int c2 = 0; c2 < 4; ++c2) acc2[c2] = (f32x4){0.f, 0.f, 0.f, 0.f};
#pragma unroll
        for (int kk = 0; kk < 4; ++kk)
#pragma unroll
            for (int c2 = 0; c2 < 4; ++c2)
                acc2[c2] = __builtin_amdgcn_mfma_f32_16x16x32_bf16(bw[c2][kk], a[kk], acc2[c2], 0, 0, 0);

        if (node < n) {
#pragma unroll
            for (int c2 = 0; c2 < 4; ++c2) {
                uint2 w;
                w.x = (unsigned)f2bf(dn * acc2[c2][0]) | ((unsigned)f2bf(dn * acc2[c2][1]) << 16);
                w.y = (unsigned)f2bf(dn * acc2[c2][2]) | ((unsigned)f2bf(dn * acc2[c2][3]) << 16);
                *reinterpret_cast<uint2*>(op + (h * 4 + c2) * 16) = w;
            }
        }
    }
}

// ---------------- standalone gather-aggregate (layer 2 output, f32) ----------------
__global__ __launch_bounds__(256, 8) void k_gather_agg(const unsigned short* __restrict__ hs,
                                                       const int* __restrict__ starts,
                                                       const int* __restrict__ esrc,
                                                       const float* __restrict__ dis,
                                                       const float* __restrict__ b,
                                                       float* __restrict__ outv, int n) {
    const int lane = threadIdx.x & 63;
    const int wv = threadIdx.x >> 6;
    const int grp = lane >> 4;
    const int sub = lane & 15;
    const int i = (blockIdx.x * 4 + wv) * 4 + grp;
    const bool active = (i < n);
    const int ic = active ? i : (n - 1);

    const float di = dis[ic];
    const int beg = starts[ic];
    const int end = starts[ic + 1];

    float acc[8];
    {   // self-loop row
        const u32x4 u = *reinterpret_cast<const u32x4*>(hs + (size_t)ic * D + sub * 8);
#pragma unroll
        for (int e = 0; e < 4; ++e) {
            acc[2 * e] = bf_lo(u[e]);
            acc[2 * e + 1] = bf_hi(u[e]);
        }
    }
    for (int j = beg; j < end; j += 16) {
        const int cnt = min(end - j, 16);
        const int me = (sub < cnt) ? esrc[j + sub] : 0;
        accum_chunk(hs, me, cnt, grp, sub, acc);
    }

    if (!active) return;

    const float4 bv0 = reinterpret_cast<const float4*>(b)[sub * 2 + 0];
    const float4 bv1 = reinterpret_cast<const float4*>(b)[sub * 2 + 1];
    float4* op = reinterpret_cast<float4*>(outv + (size_t)i * D + sub * 8);
    op[0] = make_float4(di * acc[0] + bv0.x, di * acc[1] + bv0.y,
                        di * acc[2] + bv0.z, di * acc[3] + bv0.w);
    op[1] = make_float4(di * acc[4] + bv1.x, di * acc[5] + bv1.y,
                        di * acc[6] + bv1.z, di * acc[7] + bv1.w);
}

extern "C" void kernel_launch(void* const* d_in, const int* in_sizes, int n_in,
                              void* d_out, int out_size, void* d_ws, size_t ws_size,
                              hipStream_t stream) {
    const float* x  = (const float*)d_in[0];
    const int*   ei = (const int*)d_in[1];   // [2, E]
    const float* W1 = (const float*)d_in[2];
    const float* b1 = (const float*)d_in[3];
    const float* W2 = (const float*)d_in[4];
    const float* b2 = (const float*)d_in[5];
    float* out = (float*)d_out;

    const int n  = in_sizes[0] / D;
    const int nE = in_sizes[1] / 2;
    const int* src = ei;
    const int* dst = ei + nE;

    char* ws = (char*)d_ws;
    float*          dis    = (float*)(ws);                  // n f32
    int*            counts = (int*)(ws + (1ull  << 19));    // n i32
    int*            starts = (int*)(ws + (2ull  << 19));    // n+1 i32
    int*            esrc   = (int*)(ws + (4ull  << 19));    // nE i32 (2..4.4M)
    int*            bsum   = (int*)(ws + (6ull  << 20));    // <=128 i32
    unsigned short* hs_bf  = (unsigned short*)(ws + (8ull  << 20));  // n*128 bf16
    int*            rank   = (int*)(ws + (34ull << 20));    // nE i32
    unsigned short* wp     = (unsigned short*)(ws + (37ull << 20));  // 64KB (both layers)
    unsigned short* hs2_bf = (unsigned short*)(ws + (40ull << 20));  // n*128 bf16

    unsigned short* wp1 = wp;
    unsigned short* wp2 = wp + 2048 * 8;

    const int B = 256;
    const int gn = (n + B - 1) / B;
    const int ge4 = (nE + B * 4 - 1) / (B * 4);
    const int nB = (n + 1023) / 1024;  // <=128 for n<=131072

    // W pre-pack (both layers) + counts zero, one launch
    k_pack_zero<<<16 + gn, B, 0, stream>>>(W1, W2, wp, counts, n);

    // CSR by dst (counts also yields degrees: deg = counts + 1 self-loop)
    k_hist_rank<<<ge4, B, 0, stream>>>(dst, counts, rank, nE);
    k_scan_part<<<nB, B, 0, stream>>>(counts, bsum, dis, n);
    k_scan_final<<<nB, B, 0, stream>>>(counts, bsum, starts, n, nB);

    const int nst = (n + 63) / 64;
    const int agg_grid = (n + 15) / 16;

    // ---- FUSED: scatter (blocks < ge4) || layer-1 GEMM (blocks >= ge4) ----
    k_scatter_gemm<<<ge4 + nst, B, 0, stream>>>(src, dst, rank, starts, esrc, nE, ge4,
                                                x, wp1, dis, hs_bf, n);
    // ---- FUSED: agg1(+b1,ReLU) -> @W2 -> hs2 = dis .* (relu(agg1) @ W2) ----
    k_gather_gemm<<<nst, B, 0, stream>>>(hs_bf, starts, esrc, dis, b1, wp2, hs2_bf, n);
    // ---- layer 2 aggregation -> f32 output ----
    k_gather_agg<<<agg_grid, B, 0, stream>>>(hs2_bf, starts, esrc, dis, b2, out, n);
}

// Round 14
// 142.189 us; speedup vs baseline: 1.0880x; 1.0880x over previous
//
#include <hip/hip_runtime.h>

#define D 128

typedef __attribute__((ext_vector_type(8))) short bf16x8;
typedef __attribute__((ext_vector_type(4))) float f32x4;
typedef __attribute__((ext_vector_type(4))) unsigned u32x4;

__device__ inline unsigned short f2bf(float f) {  // RNE fp32->bf16
    unsigned u = __builtin_bit_cast(unsigned, f);
    u += 0x7FFFu + ((u >> 16) & 1u);
    return (unsigned short)(u >> 16);
}
__device__ inline float bf_lo(unsigned u) { return __builtin_bit_cast(float, u << 16); }
__device__ inline float bf_hi(unsigned u) { return __builtin_bit_cast(float, u & 0xFFFF0000u); }

// ---------------- W pre-pack (both layers) + counts zero, one launch ----------------
__global__ __launch_bounds__(256) void k_pack_zero(const float* __restrict__ W1,
                                                   const float* __restrict__ W2,
                                                   unsigned short* __restrict__ wp,
                                                   int* __restrict__ counts, int n) {
    if (blockIdx.x < 16) {
        const int t = blockIdx.x * 256 + threadIdx.x;  // 0..4095
        const float* W = (t < 2048) ? W1 : W2;
        const int tt = t & 2047;
        const int lane = tt & 63;
        const int frag = tt >> 6;  // 0..31
        const int ct = frag >> 2;
        const int kk = frag & 3;
        const int col16 = lane & 15;
        const int kgrp = lane >> 4;
        bf16x8 d;
#pragma unroll
        for (int e = 0; e < 8; ++e)
            d[e] = (short)f2bf(W[(kk * 32 + kgrp * 8 + e) * D + ct * 16 + col16]);
        *reinterpret_cast<bf16x8*>(wp + (size_t)t * 8) = d;
    } else {
        const int i = (blockIdx.x - 16) * 256 + threadIdx.x;
        if (i < n) counts[i] = 0;
    }
}

// Histogram that also records each edge's rank within its dst segment.
__global__ void k_hist_rank(const int* __restrict__ dst, int* __restrict__ counts,
                            int* __restrict__ rank, int nE) {
    int e4 = (blockIdx.x * blockDim.x + threadIdx.x) * 4;
    if (e4 + 4 <= nE) {
        const int4 d = *reinterpret_cast<const int4*>(dst + e4);
        int4 r;
        r.x = atomicAdd(&counts[d.x], 1);
        r.y = atomicAdd(&counts[d.y], 1);
        r.z = atomicAdd(&counts[d.z], 1);
        r.w = atomicAdd(&counts[d.w], 1);
        *reinterpret_cast<int4*>(rank + e4) = r;
    } else {
        for (int e = e4; e < nE; ++e) rank[e] = atomicAdd(&counts[dst[e]], 1);
    }
}

// Pass 1: per-block (1024-element tile) sums; fused dis = rsqrt(counts+1).
__global__ __launch_bounds__(256) void k_scan_part(const int* __restrict__ counts,
                                                   int* __restrict__ bsum,
                                                   float* __restrict__ dis, int n) {
    const int t = threadIdx.x;
    const int base = blockIdx.x * 1024 + t * 4;
    int4 c = make_int4(0, 0, 0, 0);
    if (base + 4 <= n) {
        c = *reinterpret_cast<const int4*>(counts + base);
        float4 dv;
        dv.x = rsqrtf((float)(c.x + 1));
        dv.y = rsqrtf((float)(c.y + 1));
        dv.z = rsqrtf((float)(c.z + 1));
        dv.w = rsqrtf((float)(c.w + 1));
        *reinterpret_cast<float4*>(dis + base) = dv;
    } else if (base < n) {
        int cc[4] = {0, 0, 0, 0};
        for (int k = 0; k < 4; ++k)
            if (base + k < n) {
                cc[k] = counts[base + k];
                dis[base + k] = rsqrtf((float)(cc[k] + 1));
            }
        c.x = cc[0]; c.y = cc[1]; c.z = cc[2]; c.w = cc[3];
    }
    __shared__ int red[256];
    red[t] = c.x + c.y + c.z + c.w;
    __syncthreads();
    for (int off = 128; off > 0; off >>= 1) {
        if (t < off) red[t] += red[t + off];
        __syncthreads();
    }
    if (t == 0) bsum[blockIdx.x] = red[0];
}

// Pass 2: scan block sums in LDS, local-scan tile, write starts.
__global__ __launch_bounds__(256) void k_scan_final(const int* __restrict__ counts,
                                                    const int* __restrict__ bsum,
                                                    int* __restrict__ starts, int n, int nB) {
    __shared__ int sb[128];
    __shared__ int ts[256];
    const int t = threadIdx.x;
    const int b = blockIdx.x;

    if (t < 128) sb[t] = (t < nB) ? bsum[t] : 0;
    __syncthreads();
    for (int off = 1; off < 128; off <<= 1) {
        int add = (t < 128 && t >= off) ? sb[t - off] : 0;
        __syncthreads();
        if (t < 128) sb[t] += add;
        __syncthreads();
    }
    const int block_off = (b > 0) ? sb[b - 1] : 0;

    const int base = b * 1024 + t * 4;
    int4 c = make_int4(0, 0, 0, 0);
    if (base + 4 <= n) {
        c = *reinterpret_cast<const int4*>(counts + base);
    } else if (base < n) {
        if (base + 0 < n) c.x = counts[base + 0];
        if (base + 1 < n) c.y = counts[base + 1];
        if (base + 2 < n) c.z = counts[base + 2];
    }
    const int s = c.x + c.y + c.z + c.w;
    ts[t] = s;
    __syncthreads();
    for (int off = 1; off < 256; off <<= 1) {
        int add = (t >= off) ? ts[t - off] : 0;
        __syncthreads();
        ts[t] += add;
        __syncthreads();
    }
    int excl = block_off + ts[t] - s;

    int4 w;
    w.x = excl;
    w.y = w.x + c.x;
    w.z = w.y + c.y;
    w.w = w.z + c.z;
    if (base + 4 <= n) {
        *reinterpret_cast<int4*>(starts + base) = w;
    } else if (base < n) {
        if (base + 0 < n) starts[base + 0] = w.x;
        if (base + 1 < n) starts[base + 1] = w.y;
        if (base + 2 < n) starts[base + 2] = w.z;
    }
    if (b == 0 && t == 0) starts[n] = sb[nB - 1];  // = nE
}

// ---------------- FUSED scatter + layer-1 GEMM (independent work, one launch) ----
__global__ __launch_bounds__(256, 3) void k_scatter_gemm(const int* __restrict__ src,
                                                         const int* __restrict__ dst,
                                                         const int* __restrict__ rank,
                                                         const int* __restrict__ starts,
                                                         int* __restrict__ esrc, int nE, int nsc,
                                                         const float* __restrict__ X,
                                                         const unsigned short* __restrict__ wp,
                                                         const float* __restrict__ dis,
                                                         unsigned short* __restrict__ outbf,
                                                         int n) {
    __shared__ __align__(16) unsigned short At[64 * 128];  // 16KB, swizzled
    if (blockIdx.x < nsc) {
        // ---------- scatter role ----------
        int e4 = (blockIdx.x * blockDim.x + threadIdx.x) * 4;
        if (e4 + 4 <= nE) {
            const int4 s = *reinterpret_cast<const int4*>(src + e4);
            const int4 d = *reinterpret_cast<const int4*>(dst + e4);
            const int4 r = *reinterpret_cast<const int4*>(rank + e4);
            esrc[starts[d.x] + r.x] = s.x;
            esrc[starts[d.y] + r.y] = s.y;
            esrc[starts[d.z] + r.z] = s.z;
            esrc[starts[d.w] + r.w] = s.w;
        } else {
            for (int e = e4; e < nE; ++e)
                esrc[starts[dst[e]] + rank[e]] = src[e];
        }
        return;
    }
    // ---------- GEMM role ----------
    const int st = blockIdx.x - nsc;
    const int tid = threadIdx.x;
    const int lane = tid & 63;
    const int wv = tid >> 6;
    const int col16 = lane & 15;
    const int kgrp = lane >> 4;

    float4 pf[8];
#pragma unroll
    for (int c = 0; c < 4; ++c) {
        const int idx = c * 2048 + tid * 8;
        const int row = idx >> 7;
        const int col = idx & 127;
        int grow = st * 64 + row;
        if (grow >= n) grow = n - 1;
        const float4* p = reinterpret_cast<const float4*>(X + (size_t)grow * D + col);
        pf[2 * c] = p[0];
        pf[2 * c + 1] = p[1];
    }
#pragma unroll
    for (int c = 0; c < 4; ++c) {
        const int idx = c * 2048 + tid * 8;
        const int row = idx >> 7;
        const int col = idx & 127;
        const float4 f0 = pf[2 * c], f1 = pf[2 * c + 1];
        float v[8] = {f0.x, f0.y, f0.z, f0.w, f1.x, f1.y, f1.z, f1.w};
        bf16x8 d;
#pragma unroll
        for (int e = 0; e < 8; ++e) d[e] = (short)f2bf(v[e]);
        const int waddr = row * 128 + (col ^ ((row & 7) << 3));
        *reinterpret_cast<bf16x8*>(&At[waddr]) = d;
    }
    __syncthreads();

    bf16x8 a[4];
#pragma unroll
    for (int kk = 0; kk < 4; ++kk) {
        const int raddr = (wv * 16 + col16) * 128 +
                          ((kk * 32 + kgrp * 8) ^ ((col16 & 7) << 3));
        a[kk] = *reinterpret_cast<const bf16x8*>(&At[raddr]);
    }

    const int node = st * 64 + wv * 16 + col16;
    const float dn = (node < n) ? dis[node] : 0.0f;
    unsigned short* op = outbf + (size_t)node * D + kgrp * 4;

#pragma unroll
    for (int h = 0; h < 2; ++h) {
        bf16x8 bw[4][4];
#pragma unroll
        for (int c2 = 0; c2 < 4; ++c2)
#pragma unroll
            for (int kk = 0; kk < 4; ++kk)
                bw[c2][kk] = *reinterpret_cast<const bf16x8*>(
                        wp + (size_t)(((h * 4 + c2) * 4 + kk) * 64 + lane) * 8);

        f32x4 acc[4];
#pragma unroll
        for (int c2 = 0; c2 < 4; ++c2) acc[c2] = (f32x4){0.f, 0.f, 0.f, 0.f};
#pragma unroll
        for (int kk = 0; kk < 4; ++kk)
#pragma unroll
            for (int c2 = 0; c2 < 4; ++c2)  // SWAPPED operands: D = (X@W)^T
                acc[c2] = __builtin_amdgcn_mfma_f32_16x16x32_bf16(bw[c2][kk], a[kk], acc[c2], 0, 0, 0);

        if (node < n) {
#pragma unroll
            for (int c2 = 0; c2 < 4; ++c2) {
                uint2 w;
                w.x = (unsigned)f2bf(dn * acc[c2][0]) | ((unsigned)f2bf(dn * acc[c2][1]) << 16);
                w.y = (unsigned)f2bf(dn * acc[c2][2]) | ((unsigned)f2bf(dn * acc[c2][3]) << 16);
                *reinterpret_cast<uint2*>(op + (h * 4 + c2) * 16) = w;
            }
        }
    }
}

// ---------------- gather chunk core: 8-deep pipelined row accumulate ----------------
__device__ __forceinline__ void accum_chunk(const unsigned short* __restrict__ hs,
                                            int myedge, int cnt, int grp, int sub,
                                            float acc[8]) {
    auto row16 = [&](int s) -> u32x4 {
        return *reinterpret_cast<const u32x4*>(hs + (size_t)s * D + sub * 8);
    };
    for (int k = 0; k < cnt; k += 8) {
        u32x4 u[8];
#pragma unroll
        for (int q = 0; q < 8; ++q) {
            const int tq = min(k + q, cnt - 1);  // clamp: dupes hit L1
            const int s = __shfl(myedge, (grp << 4) | tq);
            u[q] = row16(s);
        }
        const int rem = cnt - k;
#pragma unroll
        for (int q = 0; q < 8; ++q) {
            if (q < rem) {
#pragma unroll
                for (int e = 0; e < 4; ++e) {
                    acc[2 * e] += bf_lo(u[q][e]);
                    acc[2 * e + 1] += bf_hi(u[q][e]);
                }
            }
        }
    }
}

// ---------------- FUSED gather + GEMM (layer 1 agg + layer 2 matmul) ----------------
// R13: R10 body (52 VGPR, no spills) at 128 threads / 32-row tiles -> grid 3126,
// ~12 blocks/CU resident. More independent gather streams per CU + finer tail,
// zero register-pressure change. NO aggressive launch_bounds (R12 spill lesson).
__global__ __launch_bounds__(128, 4) void k_gather_gemm(const unsigned short* __restrict__ hs,
                                                        const int* __restrict__ starts,
                                                        const int* __restrict__ esrc,
                                                        const float* __restrict__ dis,
                                                        const float* __restrict__ bias,
                                                        const unsigned short* __restrict__ wp,
                                                        unsigned short* __restrict__ outbf,
                                                        int n) {
    __shared__ __align__(16) unsigned short At[32 * 128];  // 8KB, swizzled
    const int tid = threadIdx.x;
    const int lane = tid & 63;
    const int wv = tid >> 6;     // 0..1
    const int col16 = lane & 15;
    const int kgrp = lane >> 4;
    const int grp = lane >> 4;   // node within 4-node quad
    const int sub = lane & 15;   // lane within node
    const int st = blockIdx.x;

    const float4 bv0 = reinterpret_cast<const float4*>(bias)[sub * 2 + 0];
    const float4 bv1 = reinterpret_cast<const float4*>(bias)[sub * 2 + 1];

    // ---- metadata for all 4 quads: independent loads, all in flight together ----
    int ic[4], beg[4], end[4], cnt0[4], my[4];
    float di[4];
    u32x4 selfrow[4];
#pragma unroll
    for (int p = 0; p < 4; ++p) {
        const int i = st * 32 + wv * 16 + p * 4 + grp;
        ic[p] = (i < n) ? i : (n - 1);
    }
#pragma unroll
    for (int p = 0; p < 4; ++p) {
        beg[p] = starts[ic[p]];
        end[p] = starts[ic[p] + 1];
        di[p] = dis[ic[p]];
        selfrow[p] = *reinterpret_cast<const u32x4*>(hs + (size_t)ic[p] * D + sub * 8);
    }
#pragma unroll
    for (int p = 0; p < 4; ++p) {
        cnt0[p] = min(end[p] - beg[p], 16);
        my[p] = (sub < cnt0[p]) ? esrc[beg[p] + sub] : 0;
    }

    // ---- accumulate per quad (metadata already in flight) ----
#pragma unroll
    for (int p = 0; p < 4; ++p) {
        float acc[8];
#pragma unroll
        for (int e = 0; e < 4; ++e) {
            acc[2 * e] = bf_lo(selfrow[p][e]);
            acc[2 * e + 1] = bf_hi(selfrow[p][e]);
        }
        if (cnt0[p] > 0) accum_chunk(hs, my[p], cnt0[p], grp, sub, acc);
        // rare chunks beyond 16 edges
        for (int j = beg[p] + 16; j < end[p]; j += 16) {
            const int cnt = min(end[p] - j, 16);
            const int me = (sub < cnt) ? esrc[j + sub] : 0;
            accum_chunk(hs, me, cnt, grp, sub, acc);
        }

        float o[8];
        o[0] = di[p] * acc[0] + bv0.x; o[1] = di[p] * acc[1] + bv0.y;
        o[2] = di[p] * acc[2] + bv0.z; o[3] = di[p] * acc[3] + bv0.w;
        o[4] = di[p] * acc[4] + bv1.x; o[5] = di[p] * acc[5] + bv1.y;
        o[6] = di[p] * acc[6] + bv1.z; o[7] = di[p] * acc[7] + bv1.w;

        u32x4 w;  // ReLU + bf16 pack
#pragma unroll
        for (int e = 0; e < 4; ++e)
            w[e] = (unsigned)f2bf(fmaxf(o[2 * e], 0.0f)) |
                   ((unsigned)f2bf(fmaxf(o[2 * e + 1], 0.0f)) << 16);
        const int lrow = wv * 16 + p * 4 + grp;
        const int waddr = lrow * 128 + ((sub * 8) ^ ((lrow & 7) << 3));
        *reinterpret_cast<u32x4*>(&At[waddr]) = w;
    }
    __syncthreads();

    // ---- GEMM phase ----
    bf16x8 a[4];
#pragma unroll
    for (int kk = 0; kk < 4; ++kk) {
        const int raddr = (wv * 16 + col16) * 128 +
                          ((kk * 32 + kgrp * 8) ^ ((col16 & 7) << 3));
        a[kk] = *reinterpret_cast<const bf16x8*>(&At[raddr]);
    }

    const int node = st * 32 + wv * 16 + col16;
    const float dn = (node < n) ? dis[node] : 0.0f;
    unsigned short* op = outbf + (size_t)node * D + kgrp * 4;

#pragma unroll
    for (int h = 0; h < 2; ++h) {
        bf16x8 bw[4][4];
#pragma unroll
        for (int c2 = 0; c2 < 4; ++c2)
#pragma unroll
            for (int kk = 0; kk < 4; ++kk)
                bw[c2][kk] = *reinterpret_cast<const bf16x8*>(
                        wp + (size_t)(((h * 4 + c2) * 4 + kk) * 64 + lane) * 8);

        f32x4 acc2[4];
#pragma unroll
        for (int c2 = 0; c2 < 4; ++c2) acc2[c2] = (f32x4){0.f, 0.f, 0.f, 0.f};
#pragma unroll
        for (int kk = 0; kk < 4; ++kk)
#pragma unroll
            for (int c2 = 0; c2 < 4; ++c2)
                acc2[c2] = __builtin_amdgcn_mfma_f32_16x16x32_bf16(bw[c2][kk], a[kk], acc2[c2], 0, 0, 0);

        if (node < n) {
#pragma unroll
            for (int c2 = 0; c2 < 4; ++c2) {
                uint2 w;
                w.x = (unsigned)f2bf(dn * acc2[c2][0]) | ((unsigned)f2bf(dn * acc2[c2][1]) << 16);
                w.y = (unsigned)f2bf(dn * acc2[c2][2]) | ((unsigned)f2bf(dn * acc2[c2][3]) << 16);
                *reinterpret_cast<uint2*>(op + (h * 4 + c2) * 16) = w;
            }
        }
    }
}

// ---------------- standalone gather-aggregate (layer 2 output, f32) ----------------
__global__ __launch_bounds__(256) void k_gather_agg(const unsigned short* __restrict__ hs,
                                                    const int* __restrict__ starts,
                                                    const int* __restrict__ esrc,
                                                    const float* __restrict__ dis,
                                                    const float* __restrict__ b,
                                                    float* __restrict__ outv, int n) {
    const int lane = threadIdx.x & 63;
    const int wv = threadIdx.x >> 6;
    const int grp = lane >> 4;
    const int sub = lane & 15;
    const int i = (blockIdx.x * 4 + wv) * 4 + grp;
    const bool active = (i < n);
    const int ic = active ? i : (n - 1);

    const float di = dis[ic];
    const int beg = starts[ic];
    const int end = starts[ic + 1];

    float acc[8];
    {   // self-loop row
        const u32x4 u = *reinterpret_cast<const u32x4*>(hs + (size_t)ic * D + sub * 8);
#pragma unroll
        for (int e = 0; e < 4; ++e) {
            acc[2 * e] = bf_lo(u[e]);
            acc[2 * e + 1] = bf_hi(u[e]);
        }
    }
    for (int j = beg; j < end; j += 16) {
        const int cnt = min(end - j, 16);
        const int me = (sub < cnt) ? esrc[j + sub] : 0;
        accum_chunk(hs, me, cnt, grp, sub, acc);
    }

    if (!active) return;

    const float4 bv0 = reinterpret_cast<const float4*>(b)[sub * 2 + 0];
    const float4 bv1 = reinterpret_cast<const float4*>(b)[sub * 2 + 1];
    float4* op = reinterpret_cast<float4*>(outv + (size_t)i * D + sub * 8);
    op[0] = make_float4(di * acc[0] + bv0.x, di * acc[1] + bv0.y,
                        di * acc[2] + bv0.z, di * acc[3] + bv0.w);
    op[1] = make_float4(di * acc[4] + bv1.x, di * acc[5] + bv1.y,
                        di * acc[6] + bv1.z, di * acc[7] + bv1.w);
}

extern "C" void kernel_launch(void* const* d_in, const int* in_sizes, int n_in,
                              void* d_out, int out_size, void* d_ws, size_t ws_size,
                              hipStream_t stream) {
    const float* x  = (const float*)d_in[0];
    const int*   ei = (const int*)d_in[1];   // [2, E]
    const float* W1 = (const float*)d_in[2];
    const float* b1 = (const float*)d_in[3];
    const float* W2 = (const float*)d_in[4];
    const float* b2 = (const float*)d_in[5];
    float* out = (float*)d_out;

    const int n  = in_sizes[0] / D;
    const int nE = in_sizes[1] / 2;
    const int* src = ei;
    const int* dst = ei + nE;

    char* ws = (char*)d_ws;
    float*          dis    = (float*)(ws);                  // n f32
    int*            counts = (int*)(ws + (1ull  << 19));    // n i32
    int*            starts = (int*)(ws + (2ull  << 19));    // n+1 i32
    int*            esrc   = (int*)(ws + (4ull  << 19));    // nE i32 (2..4.4M)
    int*            bsum   = (int*)(ws + (6ull  << 20));    // <=128 i32
    unsigned short* hs_bf  = (unsigned short*)(ws + (8ull  << 20));  // n*128 bf16
    int*            rank   = (int*)(ws + (34ull << 20));    // nE i32
    unsigned short* wp     = (unsigned short*)(ws + (37ull << 20));  // 64KB (both layers)
    unsigned short* hs2_bf = (unsigned short*)(ws + (40ull << 20));  // n*128 bf16

    unsigned short* wp1 = wp;
    unsigned short* wp2 = wp + 2048 * 8;

    const int B = 256;
    const int gn = (n + B - 1) / B;
    const int ge4 = (nE + B * 4 - 1) / (B * 4);
    const int nB = (n + 1023) / 1024;  // <=128 for n<=131072

    // W pre-pack (both layers) + counts zero, one launch
    k_pack_zero<<<16 + gn, B, 0, stream>>>(W1, W2, wp, counts, n);

    // CSR by dst (counts also yields degrees: deg = counts + 1 self-loop)
    k_hist_rank<<<ge4, B, 0, stream>>>(dst, counts, rank, nE);
    k_scan_part<<<nB, B, 0, stream>>>(counts, bsum, dis, n);
    k_scan_final<<<nB, B, 0, stream>>>(counts, bsum, starts, n, nB);

    const int nst = (n + 63) / 64;
    const int nst32 = (n + 31) / 32;
    const int agg_grid = (n + 15) / 16;

    // ---- FUSED: scatter (blocks < ge4) || layer-1 GEMM (blocks >= ge4) ----
    k_scatter_gemm<<<ge4 + nst, B, 0, stream>>>(src, dst, rank, starts, esrc, nE, ge4,
                                                x, wp1, dis, hs_bf, n);
    // ---- FUSED: agg1(+b1,ReLU) -> @W2 -> hs2 = dis .* (relu(agg1) @ W2) ----
    k_gather_gemm<<<nst32, 128, 0, stream>>>(hs_bf, starts, esrc, dis, b1, wp2, hs2_bf, n);
    // ---- layer 2 aggregation -> f32 output ----
    k_gather_agg<<<agg_grid, B, 0, stream>>>(hs2_bf, starts, esrc, dis, b2, out, n);
}

// Round 15
// 141.653 us; speedup vs baseline: 1.0921x; 1.0038x over previous
//
#include <hip/hip_runtime.h>

#define D 128

typedef __attribute__((ext_vector_type(8))) short bf16x8;
typedef __attribute__((ext_vector_type(4))) float f32x4;
typedef __attribute__((ext_vector_type(4))) unsigned u32x4;

__device__ inline unsigned short f2bf(float f) {  // RNE fp32->bf16
    unsigned u = __builtin_bit_cast(unsigned, f);
    u += 0x7FFFu + ((u >> 16) & 1u);
    return (unsigned short)(u >> 16);
}
__device__ inline float bf_lo(unsigned u) { return __builtin_bit_cast(float, u << 16); }
__device__ inline float bf_hi(unsigned u) { return __builtin_bit_cast(float, u & 0xFFFF0000u); }

// ---------------- W pre-pack (both layers) + counts zero, one launch ----------------
__global__ __launch_bounds__(256) void k_pack_zero(const float* __restrict__ W1,
                                                   const float* __restrict__ W2,
                                                   unsigned short* __restrict__ wp,
                                                   int* __restrict__ counts, int n) {
    if (blockIdx.x < 16) {
        const int t = blockIdx.x * 256 + threadIdx.x;  // 0..4095
        const float* W = (t < 2048) ? W1 : W2;
        const int tt = t & 2047;
        const int lane = tt & 63;
        const int frag = tt >> 6;  // 0..31
        const int ct = frag >> 2;
        const int kk = frag & 3;
        const int col16 = lane & 15;
        const int kgrp = lane >> 4;
        bf16x8 d;
#pragma unroll
        for (int e = 0; e < 8; ++e)
            d[e] = (short)f2bf(W[(kk * 32 + kgrp * 8 + e) * D + ct * 16 + col16]);
        *reinterpret_cast<bf16x8*>(wp + (size_t)t * 8) = d;
    } else {
        const int i = (blockIdx.x - 16) * 256 + threadIdx.x;
        if (i < n) counts[i] = 0;
    }
}

// ---------------- FUSED hist_rank + layer-1 GEMM (independent work, one launch) ----
// Blocks [0, nsc): histogram + per-edge rank (atomicAdd return value).
// Blocks [nsc, nsc+nst): 64-row MFMA tile of h = x @ W1 (UNSCALED - no dis dep!).
__global__ __launch_bounds__(256, 3) void k_hist_gemm(const int* __restrict__ dst,
                                                      int* __restrict__ counts,
                                                      int* __restrict__ rank, int nE, int nsc,
                                                      const float* __restrict__ X,
                                                      const unsigned short* __restrict__ wp,
                                                      unsigned short* __restrict__ outbf,
                                                      int n) {
    __shared__ __align__(16) unsigned short At[64 * 128];  // 16KB, swizzled
    if (blockIdx.x < nsc) {
        // ---------- histogram role ----------
        int e4 = (blockIdx.x * blockDim.x + threadIdx.x) * 4;
        if (e4 + 4 <= nE) {
            const int4 d = *reinterpret_cast<const int4*>(dst + e4);
            int4 r;
            r.x = atomicAdd(&counts[d.x], 1);
            r.y = atomicAdd(&counts[d.y], 1);
            r.z = atomicAdd(&counts[d.z], 1);
            r.w = atomicAdd(&counts[d.w], 1);
            *reinterpret_cast<int4*>(rank + e4) = r;
        } else {
            for (int e = e4; e < nE; ++e) rank[e] = atomicAdd(&counts[dst[e]], 1);
        }
        return;
    }
    // ---------- GEMM role ----------
    const int st = blockIdx.x - nsc;
    const int tid = threadIdx.x;
    const int lane = tid & 63;
    const int wv = tid >> 6;
    const int col16 = lane & 15;
    const int kgrp = lane >> 4;

    float4 pf[8];
#pragma unroll
    for (int c = 0; c < 4; ++c) {
        const int idx = c * 2048 + tid * 8;
        const int row = idx >> 7;
        const int col = idx & 127;
        int grow = st * 64 + row;
        if (grow >= n) grow = n - 1;
        const float4* p = reinterpret_cast<const float4*>(X + (size_t)grow * D + col);
        pf[2 * c] = p[0];
        pf[2 * c + 1] = p[1];
    }
#pragma unroll
    for (int c = 0; c < 4; ++c) {
        const int idx = c * 2048 + tid * 8;
        const int row = idx >> 7;
        const int col = idx & 127;
        const float4 f0 = pf[2 * c], f1 = pf[2 * c + 1];
        float v[8] = {f0.x, f0.y, f0.z, f0.w, f1.x, f1.y, f1.z, f1.w};
        bf16x8 d;
#pragma unroll
        for (int e = 0; e < 8; ++e) d[e] = (short)f2bf(v[e]);
        const int waddr = row * 128 + (col ^ ((row & 7) << 3));
        *reinterpret_cast<bf16x8*>(&At[waddr]) = d;
    }
    __syncthreads();

    bf16x8 a[4];
#pragma unroll
    for (int kk = 0; kk < 4; ++kk) {
        const int raddr = (wv * 16 + col16) * 128 +
                          ((kk * 32 + kgrp * 8) ^ ((col16 & 7) << 3));
        a[kk] = *reinterpret_cast<const bf16x8*>(&At[raddr]);
    }

    const int node = st * 64 + wv * 16 + col16;
    unsigned short* op = outbf + (size_t)node * D + kgrp * 4;

#pragma unroll
    for (int h = 0; h < 2; ++h) {
        bf16x8 bw[4][4];
#pragma unroll
        for (int c2 = 0; c2 < 4; ++c2)
#pragma unroll
            for (int kk = 0; kk < 4; ++kk)
                bw[c2][kk] = *reinterpret_cast<const bf16x8*>(
                        wp + (size_t)(((h * 4 + c2) * 4 + kk) * 64 + lane) * 8);

        f32x4 acc[4];
#pragma unroll
        for (int c2 = 0; c2 < 4; ++c2) acc[c2] = (f32x4){0.f, 0.f, 0.f, 0.f};
#pragma unroll
        for (int kk = 0; kk < 4; ++kk)
#pragma unroll
            for (int c2 = 0; c2 < 4; ++c2)  // SWAPPED operands: D = (X@W)^T
                acc[c2] = __builtin_amdgcn_mfma_f32_16x16x32_bf16(bw[c2][kk], a[kk], acc[c2], 0, 0, 0);

        if (node < n) {
#pragma unroll
            for (int c2 = 0; c2 < 4; ++c2) {
                uint2 w;  // UNSCALED epilogue (dis applied at gather time)
                w.x = (unsigned)f2bf(acc[c2][0]) | ((unsigned)f2bf(acc[c2][1]) << 16);
                w.y = (unsigned)f2bf(acc[c2][2]) | ((unsigned)f2bf(acc[c2][3]) << 16);
                *reinterpret_cast<uint2*>(op + (h * 4 + c2) * 16) = w;
            }
        }
    }
}

// Pass 1: per-block (1024-element tile) sums; fused dis = rsqrt(counts+1).
__global__ __launch_bounds__(256) void k_scan_part(const int* __restrict__ counts,
                                                   int* __restrict__ bsum,
                                                   float* __restrict__ dis, int n) {
    const int t = threadIdx.x;
    const int base = blockIdx.x * 1024 + t * 4;
    int4 c = make_int4(0, 0, 0, 0);
    if (base + 4 <= n) {
        c = *reinterpret_cast<const int4*>(counts + base);
        float4 dv;
        dv.x = rsqrtf((float)(c.x + 1));
        dv.y = rsqrtf((float)(c.y + 1));
        dv.z = rsqrtf((float)(c.z + 1));
        dv.w = rsqrtf((float)(c.w + 1));
        *reinterpret_cast<float4*>(dis + base) = dv;
    } else if (base < n) {
        int cc[4] = {0, 0, 0, 0};
        for (int k = 0; k < 4; ++k)
            if (base + k < n) {
                cc[k] = counts[base + k];
                dis[base + k] = rsqrtf((float)(cc[k] + 1));
            }
        c.x = cc[0]; c.y = cc[1]; c.z = cc[2]; c.w = cc[3];
    }
    __shared__ int red[256];
    red[t] = c.x + c.y + c.z + c.w;
    __syncthreads();
    for (int off = 128; off > 0; off >>= 1) {
        if (t < off) red[t] += red[t + off];
        __syncthreads();
    }
    if (t == 0) bsum[blockIdx.x] = red[0];
}

// Pass 2: scan block sums in LDS, local-scan tile, write starts.
__global__ __launch_bounds__(256) void k_scan_final(const int* __restrict__ counts,
                                                    const int* __restrict__ bsum,
                                                    int* __restrict__ starts, int n, int nB) {
    __shared__ int sb[128];
    __shared__ int ts[256];
    const int t = threadIdx.x;
    const int b = blockIdx.x;

    if (t < 128) sb[t] = (t < nB) ? bsum[t] : 0;
    __syncthreads();
    for (int off = 1; off < 128; off <<= 1) {
        int add = (t < 128 && t >= off) ? sb[t - off] : 0;
        __syncthreads();
        if (t < 128) sb[t] += add;
        __syncthreads();
    }
    const int block_off = (b > 0) ? sb[b - 1] : 0;

    const int base = b * 1024 + t * 4;
    int4 c = make_int4(0, 0, 0, 0);
    if (base + 4 <= n) {
        c = *reinterpret_cast<const int4*>(counts + base);
    } else if (base < n) {
        if (base + 0 < n) c.x = counts[base + 0];
        if (base + 1 < n) c.y = counts[base + 1];
        if (base + 2 < n) c.z = counts[base + 2];
    }
    const int s = c.x + c.y + c.z + c.w;
    ts[t] = s;
    __syncthreads();
    for (int off = 1; off < 256; off <<= 1) {
        int add = (t >= off) ? ts[t - off] : 0;
        __syncthreads();
        ts[t] += add;
        __syncthreads();
    }
    int excl = block_off + ts[t] - s;

    int4 w;
    w.x = excl;
    w.y = w.x + c.x;
    w.z = w.y + c.y;
    w.w = w.z + c.z;
    if (base + 4 <= n) {
        *reinterpret_cast<int4*>(starts + base) = w;
    } else if (base < n) {
        if (base + 0 < n) starts[base + 0] = w.x;
        if (base + 1 < n) starts[base + 1] = w.y;
        if (base + 2 < n) starts[base + 2] = w.z;
    }
    if (b == 0 && t == 0) starts[n] = sb[nB - 1];  // = nE
}

// Atomic-free scatter: position = starts[dst] + precomputed rank.
__global__ void k_scatter_nr(const int* __restrict__ src, const int* __restrict__ dst,
                             const int* __restrict__ rank, const int* __restrict__ starts,
                             int* __restrict__ esrc, int nE) {
    int e4 = (blockIdx.x * blockDim.x + threadIdx.x) * 4;
    if (e4 + 4 <= nE) {
        const int4 s = *reinterpret_cast<const int4*>(src + e4);
        const int4 d = *reinterpret_cast<const int4*>(dst + e4);
        const int4 r = *reinterpret_cast<const int4*>(rank + e4);
        esrc[starts[d.x] + r.x] = s.x;
        esrc[starts[d.y] + r.y] = s.y;
        esrc[starts[d.z] + r.z] = s.z;
        esrc[starts[d.w] + r.w] = s.w;
    } else {
        for (int e = e4; e < nE; ++e)
            esrc[starts[dst[e]] + rank[e]] = src[e];
    }
}

// ---------------- gather chunk cores: 8-deep pipelined row accumulate ----------------
// Unweighted (pre-scaled rows):
__device__ __forceinline__ void accum_chunk(const unsigned short* __restrict__ hs,
                                            int myedge, int cnt, int grp, int sub,
                                            float acc[8]) {
    auto row16 = [&](int s) -> u32x4 {
        return *reinterpret_cast<const u32x4*>(hs + (size_t)s * D + sub * 8);
    };
    for (int k = 0; k < cnt; k += 8) {
        u32x4 u[8];
#pragma unroll
        for (int q = 0; q < 8; ++q) {
            const int tq = min(k + q, cnt - 1);  // clamp: dupes hit L1
            const int s = __shfl(myedge, (grp << 4) | tq);
            u[q] = row16(s);
        }
        const int rem = cnt - k;
#pragma unroll
        for (int q = 0; q < 8; ++q) {
            if (q < rem) {
#pragma unroll
                for (int e = 0; e < 4; ++e) {
                    acc[2 * e] += bf_lo(u[q][e]);
                    acc[2 * e + 1] += bf_hi(u[q][e]);
                }
            }
        }
    }
}

// Weighted (unscaled rows; weight dis[src] shfl'd alongside the index):
__device__ __forceinline__ void accum_chunk_w(const unsigned short* __restrict__ hs,
                                              int myedge, float myw, int cnt, int grp, int sub,
                                              float acc[8]) {
    auto row16 = [&](int s) -> u32x4 {
        return *reinterpret_cast<const u32x4*>(hs + (size_t)s * D + sub * 8);
    };
    for (int k = 0; k < cnt; k += 8) {
        u32x4 u[8];
        float w[8];
#pragma unroll
        for (int q = 0; q < 8; ++q) {
            const int tq = min(k + q, cnt - 1);
            const int sl = (grp << 4) | tq;
            const int s = __shfl(myedge, sl);
            w[q] = __shfl(myw, sl);
            u[q] = row16(s);
        }
        const int rem = cnt - k;
#pragma unroll
        for (int q = 0; q < 8; ++q) {
            if (q < rem) {
#pragma unroll
                for (int e = 0; e < 4; ++e) {
                    acc[2 * e] += w[q] * bf_lo(u[q][e]);
                    acc[2 * e + 1] += w[q] * bf_hi(u[q][e]);
                }
            }
        }
    }
}

// ---------------- FUSED gather + GEMM (layer 1 agg + layer 2 matmul) ----------------
// R14: h is UNSCALED; dis[src] gathered per edge (4B, shfl-broadcast) and applied
// via FMA. agg = dis_i * (sum dis_s*h[s] + dis_i*h[i]) + b. 128 thr / 32-row tiles.
__global__ __launch_bounds__(128, 4) void k_gather_gemm(const unsigned short* __restrict__ hs,
                                                        const int* __restrict__ starts,
                                                        const int* __restrict__ esrc,
                                                        const float* __restrict__ dis,
                                                        const float* __restrict__ bias,
                                                        const unsigned short* __restrict__ wp,
                                                        unsigned short* __restrict__ outbf,
                                                        int n) {
    __shared__ __align__(16) unsigned short At[32 * 128];  // 8KB, swizzled
    const int tid = threadIdx.x;
    const int lane = tid & 63;
    const int wv = tid >> 6;     // 0..1
    const int col16 = lane & 15;
    const int kgrp = lane >> 4;
    const int grp = lane >> 4;   // node within 4-node quad
    const int sub = lane & 15;   // lane within node
    const int st = blockIdx.x;

    const float4 bv0 = reinterpret_cast<const float4*>(bias)[sub * 2 + 0];
    const float4 bv1 = reinterpret_cast<const float4*>(bias)[sub * 2 + 1];

    // ---- metadata for all 4 quads: independent loads, all in flight together ----
    int ic[4], beg[4], end[4], cnt0[4], my[4];
    float di[4], wd[4];
    u32x4 selfrow[4];
#pragma unroll
    for (int p = 0; p < 4; ++p) {
        const int i = st * 32 + wv * 16 + p * 4 + grp;
        ic[p] = (i < n) ? i : (n - 1);
    }
#pragma unroll
    for (int p = 0; p < 4; ++p) {
        beg[p] = starts[ic[p]];
        end[p] = starts[ic[p] + 1];
        di[p] = dis[ic[p]];
        selfrow[p] = *reinterpret_cast<const u32x4*>(hs + (size_t)ic[p] * D + sub * 8);
    }
#pragma unroll
    for (int p = 0; p < 4; ++p) {
        cnt0[p] = min(end[p] - beg[p], 16);
        my[p] = (sub < cnt0[p]) ? esrc[beg[p] + sub] : 0;
    }
#pragma unroll
    for (int p = 0; p < 4; ++p)
        wd[p] = (sub < cnt0[p]) ? dis[my[p]] : 0.0f;

    // ---- accumulate per quad (metadata already in flight) ----
#pragma unroll
    for (int p = 0; p < 4; ++p) {
        float acc[8];
#pragma unroll
        for (int e = 0; e < 4; ++e) {  // self term: dis_i * h[i]
            acc[2 * e] = di[p] * bf_lo(selfrow[p][e]);
            acc[2 * e + 1] = di[p] * bf_hi(selfrow[p][e]);
        }
        if (cnt0[p] > 0) accum_chunk_w(hs, my[p], wd[p], cnt0[p], grp, sub, acc);
        // rare chunks beyond 16 edges
        for (int j = beg[p] + 16; j < end[p]; j += 16) {
            const int cnt = min(end[p] - j, 16);
            const int me = (sub < cnt) ? esrc[j + sub] : 0;
            const float mw = (sub < cnt) ? dis[me] : 0.0f;
            accum_chunk_w(hs, me, mw, cnt, grp, sub, acc);
        }

        float o[8];
        o[0] = di[p] * acc[0] + bv0.x; o[1] = di[p] * acc[1] + bv0.y;
        o[2] = di[p] * acc[2] + bv0.z; o[3] = di[p] * acc[3] + bv0.w;
        o[4] = di[p] * acc[4] + bv1.x; o[5] = di[p] * acc[5] + bv1.y;
        o[6] = di[p] * acc[6] + bv1.z; o[7] = di[p] * acc[7] + bv1.w;

        u32x4 w;  // ReLU + bf16 pack
#pragma unroll
        for (int e = 0; e < 4; ++e)
            w[e] = (unsigned)f2bf(fmaxf(o[2 * e], 0.0f)) |
                   ((unsigned)f2bf(fmaxf(o[2 * e + 1], 0.0f)) << 16);
        const int lrow = wv * 16 + p * 4 + grp;
        const int waddr = lrow * 128 + ((sub * 8) ^ ((lrow & 7) << 3));
        *reinterpret_cast<u32x4*>(&At[waddr]) = w;
    }
    __syncthreads();

    // ---- GEMM phase ----
    bf16x8 a[4];
#pragma unroll
    for (int kk = 0; kk < 4; ++kk) {
        const int raddr = (wv * 16 + col16) * 128 +
                          ((kk * 32 + kgrp * 8) ^ ((col16 & 7) << 3));
        a[kk] = *reinterpret_cast<const bf16x8*>(&At[raddr]);
    }

    const int node = st * 32 + wv * 16 + col16;
    const float dn = (node < n) ? dis[node] : 0.0f;
    unsigned short* op = outbf + (size_t)node * D + kgrp * 4;

#pragma unroll
    for (int h = 0; h < 2; ++h) {
        bf16x8 bw[4][4];
#pragma unroll
        for (int c2 = 0; c2 < 4; ++c2)
#pragma unroll
            for (int kk = 0; kk < 4; ++kk)
                bw[c2][kk] = *reinterpret_cast<const bf16x8*>(
                        wp + (size_t)(((h * 4 + c2) * 4 + kk) * 64 + lane) * 8);

        f32x4 acc2[4];
#pragma unroll
        for (int c2 = 0; c2 < 4; ++c2) acc2[c2] = (f32x4){0.f, 0.f, 0.f, 0.f};
#pragma unroll
        for (int kk = 0; kk < 4; ++kk)
#pragma unroll
            for (int c2 = 0; c2 < 4; ++c2)
                acc2[c2] = __builtin_amdgcn_mfma_f32_16x16x32_bf16(bw[c2][kk], a[kk], acc2[c2], 0, 0, 0);

        if (node < n) {
#pragma unroll
            for (int c2 = 0; c2 < 4; ++c2) {
                uint2 w;  // hs2 pre-scaled by dis (gather_agg stays unweighted)
                w.x = (unsigned)f2bf(dn * acc2[c2][0]) | ((unsigned)f2bf(dn * acc2[c2][1]) << 16);
                w.y = (unsigned)f2bf(dn * acc2[c2][2]) | ((unsigned)f2bf(dn * acc2[c2][3]) << 16);
                *reinterpret_cast<uint2*>(op + (h * 4 + c2) * 16) = w;
            }
        }
    }
}

// ---------------- standalone gather-aggregate (layer 2 output, f32) ----------------
__global__ __launch_bounds__(256) void k_gather_agg(const unsigned short* __restrict__ hs,
                                                    const int* __restrict__ starts,
                                                    const int* __restrict__ esrc,
                                                    const float* __restrict__ dis,
                                                    const float* __restrict__ b,
                                                    float* __restrict__ outv, int n) {
    const int lane = threadIdx.x & 63;
    const int wv = threadIdx.x >> 6;
    const int grp = lane >> 4;
    const int sub = lane & 15;
    const int i = (blockIdx.x * 4 + wv) * 4 + grp;
    const bool active = (i < n);
    const int ic = active ? i : (n - 1);

    const float di = dis[ic];
    const int beg = starts[ic];
    const int end = starts[ic + 1];

    float acc[8];
    {   // self-loop row
        const u32x4 u = *reinterpret_cast<const u32x4*>(hs + (size_t)ic * D + sub * 8);
#pragma unroll
        for (int e = 0; e < 4; ++e) {
            acc[2 * e] = bf_lo(u[e]);
            acc[2 * e + 1] = bf_hi(u[e]);
        }
    }
    for (int j = beg; j < end; j += 16) {
        const int cnt = min(end - j, 16);
        const int me = (sub < cnt) ? esrc[j + sub] : 0;
        accum_chunk(hs, me, cnt, grp, sub, acc);
    }

    if (!active) return;

    const float4 bv0 = reinterpret_cast<const float4*>(b)[sub * 2 + 0];
    const float4 bv1 = reinterpret_cast<const float4*>(b)[sub * 2 + 1];
    float4* op = reinterpret_cast<float4*>(outv + (size_t)i * D + sub * 8);
    op[0] = make_float4(di * acc[0] + bv0.x, di * acc[1] + bv0.y,
                        di * acc[2] + bv0.z, di * acc[3] + bv0.w);
    op[1] = make_float4(di * acc[4] + bv1.x, di * acc[5] + bv1.y,
                        di * acc[6] + bv1.z, di * acc[7] + bv1.w);
}

extern "C" void kernel_launch(void* const* d_in, const int* in_sizes, int n_in,
                              void* d_out, int out_size, void* d_ws, size_t ws_size,
                              hipStream_t stream) {
    const float* x  = (const float*)d_in[0];
    const int*   ei = (const int*)d_in[1];   // [2, E]
    const float* W1 = (const float*)d_in[2];
    const float* b1 = (const float*)d_in[3];
    const float* W2 = (const float*)d_in[4];
    const float* b2 = (const float*)d_in[5];
    float* out = (float*)d_out;

    const int n  = in_sizes[0] / D;
    const int nE = in_sizes[1] / 2;
    const int* src = ei;
    const int* dst = ei + nE;

    char* ws = (char*)d_ws;
    float*          dis    = (float*)(ws);                  // n f32
    int*            counts = (int*)(ws + (1ull  << 19));    // n i32
    int*            starts = (int*)(ws + (2ull  << 19));    // n+1 i32
    int*            esrc   = (int*)(ws + (4ull  << 19));    // nE i32 (2..4.4M)
    int*            bsum   = (int*)(ws + (6ull  << 20));    // <=128 i32
    unsigned short* hs_bf  = (unsigned short*)(ws + (8ull  << 20));  // n*128 bf16
    int*            rank   = (int*)(ws + (34ull << 20));    // nE i32
    unsigned short* wp     = (unsigned short*)(ws + (37ull << 20));  // 64KB (both layers)
    unsigned short* hs2_bf = (unsigned short*)(ws + (40ull << 20));  // n*128 bf16

    unsigned short* wp1 = wp;
    unsigned short* wp2 = wp + 2048 * 8;

    const int B = 256;
    const int gn = (n + B - 1) / B;
    const int ge4 = (nE + B * 4 - 1) / (B * 4);
    const int nB = (n + 1023) / 1024;  // <=128 for n<=131072

    const int nst = (n + 63) / 64;
    const int nst32 = (n + 31) / 32;
    const int agg_grid = (n + 15) / 16;

    // W pre-pack (both layers) + counts zero, one launch
    k_pack_zero<<<16 + gn, B, 0, stream>>>(W1, W2, wp, counts, n);

    // ---- FUSED: hist_rank (blocks < ge4) || layer-1 GEMM unscaled (blocks >= ge4) ----
    k_hist_gemm<<<ge4 + nst, B, 0, stream>>>(dst, counts, rank, nE, ge4,
                                             x, wp1, hs_bf, n);
    // CSR finish
    k_scan_part<<<nB, B, 0, stream>>>(counts, bsum, dis, n);
    k_scan_final<<<nB, B, 0, stream>>>(counts, bsum, starts, n, nB);
    k_scatter_nr<<<ge4, B, 0, stream>>>(src, dst, rank, starts, esrc, nE);

    // ---- FUSED: agg1(+b1,ReLU, per-edge dis) -> @W2 -> hs2 (pre-scaled) ----
    k_gather_gemm<<<nst32, 128, 0, stream>>>(hs_bf, starts, esrc, dis, b1, wp2, hs2_bf, n);
    // ---- layer 2 aggregation -> f32 output ----
    k_gather_agg<<<agg_grid, B, 0, stream>>>(hs2_bf, starts, esrc, dis, b2, out, n);
}

// Round 16
// 141.486 us; speedup vs baseline: 1.0934x; 1.0012x over previous
//
#include <hip/hip_runtime.h>

#define D 128

typedef __attribute__((ext_vector_type(8))) short bf16x8;
typedef __attribute__((ext_vector_type(4))) float f32x4;
typedef __attribute__((ext_vector_type(4))) unsigned u32x4;

__device__ inline unsigned short f2bf(float f) {  // RNE fp32->bf16
    unsigned u = __builtin_bit_cast(unsigned, f);
    u += 0x7FFFu + ((u >> 16) & 1u);
    return (unsigned short)(u >> 16);
}
__device__ inline float bf_lo(unsigned u) { return __builtin_bit_cast(float, u << 16); }
__device__ inline float bf_hi(unsigned u) { return __builtin_bit_cast(float, u & 0xFFFF0000u); }

// ---------------- W pre-pack (both layers) + counts zero, one launch ----------------
__global__ __launch_bounds__(256) void k_pack_zero(const float* __restrict__ W1,
                                                   const float* __restrict__ W2,
                                                   unsigned short* __restrict__ wp,
                                                   int* __restrict__ counts, int n) {
    if (blockIdx.x < 16) {
        const int t = blockIdx.x * 256 + threadIdx.x;  // 0..4095
        const float* W = (t < 2048) ? W1 : W2;
        const int tt = t & 2047;
        const int lane = tt & 63;
        const int frag = tt >> 6;  // 0..31
        const int ct = frag >> 2;
        const int kk = frag & 3;
        const int col16 = lane & 15;
        const int kgrp = lane >> 4;
        bf16x8 d;
#pragma unroll
        for (int e = 0; e < 8; ++e)
            d[e] = (short)f2bf(W[(kk * 32 + kgrp * 8 + e) * D + ct * 16 + col16]);
        *reinterpret_cast<bf16x8*>(wp + (size_t)t * 8) = d;
    } else {
        const int i = (blockIdx.x - 16) * 256 + threadIdx.x;
        if (i < n) counts[i] = 0;
    }
}

// ---------------- FUSED hist_rank + layer-1 GEMM (independent work, one launch) ----
// Blocks [0, nsc): histogram + per-edge rank (atomicAdd return value).
// Blocks [nsc, nsc+nst): 64-row MFMA tile of h = x @ W1 (UNSCALED - no dis dep).
// R15: GEMM epilogue streams W fragments per-ct (#pragma unroll 1, 16 VGPR live)
// instead of holding all 32 fragments -> stays under the 64-VGPR occupancy cliff,
// no scratch spill (R14's VGPR=32 + 46MB WRITE_SIZE pathology).
__global__ __launch_bounds__(256, 3) void k_hist_gemm(const int* __restrict__ dst,
                                                      int* __restrict__ counts,
                                                      int* __restrict__ rank, int nE, int nsc,
                                                      const float* __restrict__ X,
                                                      const unsigned short* __restrict__ wp,
                                                      unsigned short* __restrict__ outbf,
                                                      int n) {
    __shared__ __align__(16) unsigned short At[64 * 128];  // 16KB, swizzled
    if (blockIdx.x < nsc) {
        // ---------- histogram role ----------
        int e4 = (blockIdx.x * blockDim.x + threadIdx.x) * 4;
        if (e4 + 4 <= nE) {
            const int4 d = *reinterpret_cast<const int4*>(dst + e4);
            int4 r;
            r.x = atomicAdd(&counts[d.x], 1);
            r.y = atomicAdd(&counts[d.y], 1);
            r.z = atomicAdd(&counts[d.z], 1);
            r.w = atomicAdd(&counts[d.w], 1);
            *reinterpret_cast<int4*>(rank + e4) = r;
        } else {
            for (int e = e4; e < nE; ++e) rank[e] = atomicAdd(&counts[dst[e]], 1);
        }
        return;
    }
    // ---------- GEMM role ----------
    const int st = blockIdx.x - nsc;
    const int tid = threadIdx.x;
    const int lane = tid & 63;
    const int wv = tid >> 6;
    const int col16 = lane & 15;
    const int kgrp = lane >> 4;

    float4 pf[8];
#pragma unroll
    for (int c = 0; c < 4; ++c) {
        const int idx = c * 2048 + tid * 8;
        const int row = idx >> 7;
        const int col = idx & 127;
        int grow = st * 64 + row;
        if (grow >= n) grow = n - 1;
        const float4* p = reinterpret_cast<const float4*>(X + (size_t)grow * D + col);
        pf[2 * c] = p[0];
        pf[2 * c + 1] = p[1];
    }
#pragma unroll
    for (int c = 0; c < 4; ++c) {
        const int idx = c * 2048 + tid * 8;
        const int row = idx >> 7;
        const int col = idx & 127;
        const float4 f0 = pf[2 * c], f1 = pf[2 * c + 1];
        float v[8] = {f0.x, f0.y, f0.z, f0.w, f1.x, f1.y, f1.z, f1.w};
        bf16x8 d;
#pragma unroll
        for (int e = 0; e < 8; ++e) d[e] = (short)f2bf(v[e]);
        const int waddr = row * 128 + (col ^ ((row & 7) << 3));
        *reinterpret_cast<bf16x8*>(&At[waddr]) = d;
    }
    __syncthreads();

    bf16x8 a[4];
#pragma unroll
    for (int kk = 0; kk < 4; ++kk) {
        const int raddr = (wv * 16 + col16) * 128 +
                          ((kk * 32 + kgrp * 8) ^ ((col16 & 7) << 3));
        a[kk] = *reinterpret_cast<const bf16x8*>(&At[raddr]);
    }

    const int node = st * 64 + wv * 16 + col16;
    unsigned short* op = outbf + (size_t)node * D + kgrp * 4;

    // ---- per-ct streamed epilogue: 4 W frags live at a time ----
#pragma unroll 1
    for (int ct = 0; ct < 8; ++ct) {
        bf16x8 bw[4];
#pragma unroll
        for (int kk = 0; kk < 4; ++kk)
            bw[kk] = *reinterpret_cast<const bf16x8*>(
                    wp + (size_t)((ct * 4 + kk) * 64 + lane) * 8);

        f32x4 acc = (f32x4){0.f, 0.f, 0.f, 0.f};
#pragma unroll
        for (int kk = 0; kk < 4; ++kk)  // SWAPPED operands: D = (X@W)^T
            acc = __builtin_amdgcn_mfma_f32_16x16x32_bf16(bw[kk], a[kk], acc, 0, 0, 0);

        if (node < n) {
            uint2 w;  // UNSCALED epilogue (dis applied at gather time)
            w.x = (unsigned)f2bf(acc[0]) | ((unsigned)f2bf(acc[1]) << 16);
            w.y = (unsigned)f2bf(acc[2]) | ((unsigned)f2bf(acc[3]) << 16);
            *reinterpret_cast<uint2*>(op + ct * 16) = w;
        }
    }
}

// Pass 1: per-block (1024-element tile) sums; fused dis = rsqrt(counts+1).
__global__ __launch_bounds__(256) void k_scan_part(const int* __restrict__ counts,
                                                   int* __restrict__ bsum,
                                                   float* __restrict__ dis, int n) {
    const int t = threadIdx.x;
    const int base = blockIdx.x * 1024 + t * 4;
    int4 c = make_int4(0, 0, 0, 0);
    if (base + 4 <= n) {
        c = *reinterpret_cast<const int4*>(counts + base);
        float4 dv;
        dv.x = rsqrtf((float)(c.x + 1));
        dv.y = rsqrtf((float)(c.y + 1));
        dv.z = rsqrtf((float)(c.z + 1));
        dv.w = rsqrtf((float)(c.w + 1));
        *reinterpret_cast<float4*>(dis + base) = dv;
    } else if (base < n) {
        int cc[4] = {0, 0, 0, 0};
        for (int k = 0; k < 4; ++k)
            if (base + k < n) {
                cc[k] = counts[base + k];
                dis[base + k] = rsqrtf((float)(cc[k] + 1));
            }
        c.x = cc[0]; c.y = cc[1]; c.z = cc[2]; c.w = cc[3];
    }
    __shared__ int red[256];
    red[t] = c.x + c.y + c.z + c.w;
    __syncthreads();
    for (int off = 128; off > 0; off >>= 1) {
        if (t < off) red[t] += red[t + off];
        __syncthreads();
    }
    if (t == 0) bsum[blockIdx.x] = red[0];
}

// Pass 2: scan block sums in LDS, local-scan tile, write starts.
__global__ __launch_bounds__(256) void k_scan_final(const int* __restrict__ counts,
                                                    const int* __restrict__ bsum,
                                                    int* __restrict__ starts, int n, int nB) {
    __shared__ int sb[128];
    __shared__ int ts[256];
    const int t = threadIdx.x;
    const int b = blockIdx.x;

    if (t < 128) sb[t] = (t < nB) ? bsum[t] : 0;
    __syncthreads();
    for (int off = 1; off < 128; off <<= 1) {
        int add = (t < 128 && t >= off) ? sb[t - off] : 0;
        __syncthreads();
        if (t < 128) sb[t] += add;
        __syncthreads();
    }
    const int block_off = (b > 0) ? sb[b - 1] : 0;

    const int base = b * 1024 + t * 4;
    int4 c = make_int4(0, 0, 0, 0);
    if (base + 4 <= n) {
        c = *reinterpret_cast<const int4*>(counts + base);
    } else if (base < n) {
        if (base + 0 < n) c.x = counts[base + 0];
        if (base + 1 < n) c.y = counts[base + 1];
        if (base + 2 < n) c.z = counts[base + 2];
    }
    const int s = c.x + c.y + c.z + c.w;
    ts[t] = s;
    __syncthreads();
    for (int off = 1; off < 256; off <<= 1) {
        int add = (t >= off) ? ts[t - off] : 0;
        __syncthreads();
        ts[t] += add;
        __syncthreads();
    }
    int excl = block_off + ts[t] - s;

    int4 w;
    w.x = excl;
    w.y = w.x + c.x;
    w.z = w.y + c.y;
    w.w = w.z + c.z;
    if (base + 4 <= n) {
        *reinterpret_cast<int4*>(starts + base) = w;
    } else if (base < n) {
        if (base + 0 < n) starts[base + 0] = w.x;
        if (base + 1 < n) starts[base + 1] = w.y;
        if (base + 2 < n) starts[base + 2] = w.z;
    }
    if (b == 0 && t == 0) starts[n] = sb[nB - 1];  // = nE
}

// Atomic-free scatter: position = starts[dst] + precomputed rank.
__global__ void k_scatter_nr(const int* __restrict__ src, const int* __restrict__ dst,
                             const int* __restrict__ rank, const int* __restrict__ starts,
                             int* __restrict__ esrc, int nE) {
    int e4 = (blockIdx.x * blockDim.x + threadIdx.x) * 4;
    if (e4 + 4 <= nE) {
        const int4 s = *reinterpret_cast<const int4*>(src + e4);
        const int4 d = *reinterpret_cast<const int4*>(dst + e4);
        const int4 r = *reinterpret_cast<const int4*>(rank + e4);
        esrc[starts[d.x] + r.x] = s.x;
        esrc[starts[d.y] + r.y] = s.y;
        esrc[starts[d.z] + r.z] = s.z;
        esrc[starts[d.w] + r.w] = s.w;
    } else {
        for (int e = e4; e < nE; ++e)
            esrc[starts[dst[e]] + rank[e]] = src[e];
    }
}

// ---------------- gather chunk cores: 8-deep pipelined row accumulate ----------------
// Unweighted (pre-scaled rows):
__device__ __forceinline__ void accum_chunk(const unsigned short* __restrict__ hs,
                                            int myedge, int cnt, int grp, int sub,
                                            float acc[8]) {
    auto row16 = [&](int s) -> u32x4 {
        return *reinterpret_cast<const u32x4*>(hs + (size_t)s * D + sub * 8);
    };
    for (int k = 0; k < cnt; k += 8) {
        u32x4 u[8];
#pragma unroll
        for (int q = 0; q < 8; ++q) {
            const int tq = min(k + q, cnt - 1);  // clamp: dupes hit L1
            const int s = __shfl(myedge, (grp << 4) | tq);
            u[q] = row16(s);
        }
        const int rem = cnt - k;
#pragma unroll
        for (int q = 0; q < 8; ++q) {
            if (q < rem) {
#pragma unroll
                for (int e = 0; e < 4; ++e) {
                    acc[2 * e] += bf_lo(u[q][e]);
                    acc[2 * e + 1] += bf_hi(u[q][e]);
                }
            }
        }
    }
}

// Weighted (unscaled rows; weight dis[src] shfl'd alongside the index):
__device__ __forceinline__ void accum_chunk_w(const unsigned short* __restrict__ hs,
                                              int myedge, float myw, int cnt, int grp, int sub,
                                              float acc[8]) {
    auto row16 = [&](int s) -> u32x4 {
        return *reinterpret_cast<const u32x4*>(hs + (size_t)s * D + sub * 8);
    };
    for (int k = 0; k < cnt; k += 8) {
        u32x4 u[8];
        float w[8];
#pragma unroll
        for (int q = 0; q < 8; ++q) {
            const int tq = min(k + q, cnt - 1);
            const int sl = (grp << 4) | tq;
            const int s = __shfl(myedge, sl);
            w[q] = __shfl(myw, sl);
            u[q] = row16(s);
        }
        const int rem = cnt - k;
#pragma unroll
        for (int q = 0; q < 8; ++q) {
            if (q < rem) {
#pragma unroll
                for (int e = 0; e < 4; ++e) {
                    acc[2 * e] += w[q] * bf_lo(u[q][e]);
                    acc[2 * e + 1] += w[q] * bf_hi(u[q][e]);
                }
            }
        }
    }
}

// ---------------- FUSED gather + GEMM (layer 1 agg + layer 2 matmul) ----------------
// h is UNSCALED; dis[src] gathered per edge (4B, shfl-broadcast) and applied
// via FMA. agg = dis_i * (sum dis_s*h[s] + dis_i*h[i]) + b. 128 thr / 32-row tiles.
__global__ __launch_bounds__(128, 4) void k_gather_gemm(const unsigned short* __restrict__ hs,
                                                        const int* __restrict__ starts,
                                                        const int* __restrict__ esrc,
                                                        const float* __restrict__ dis,
                                                        const float* __restrict__ bias,
                                                        const unsigned short* __restrict__ wp,
                                                        unsigned short* __restrict__ outbf,
                                                        int n) {
    __shared__ __align__(16) unsigned short At[32 * 128];  // 8KB, swizzled
    const int tid = threadIdx.x;
    const int lane = tid & 63;
    const int wv = tid >> 6;     // 0..1
    const int col16 = lane & 15;
    const int kgrp = lane >> 4;
    const int grp = lane >> 4;   // node within 4-node quad
    const int sub = lane & 15;   // lane within node
    const int st = blockIdx.x;

    const float4 bv0 = reinterpret_cast<const float4*>(bias)[sub * 2 + 0];
    const float4 bv1 = reinterpret_cast<const float4*>(bias)[sub * 2 + 1];

    // ---- metadata for all 4 quads: independent loads, all in flight together ----
    int ic[4], beg[4], end[4], cnt0[4], my[4];
    float di[4], wd[4];
    u32x4 selfrow[4];
#pragma unroll
    for (int p = 0; p < 4; ++p) {
        const int i = st * 32 + wv * 16 + p * 4 + grp;
        ic[p] = (i < n) ? i : (n - 1);
    }
#pragma unroll
    for (int p = 0; p < 4; ++p) {
        beg[p] = starts[ic[p]];
        end[p] = starts[ic[p] + 1];
        di[p] = dis[ic[p]];
        selfrow[p] = *reinterpret_cast<const u32x4*>(hs + (size_t)ic[p] * D + sub * 8);
    }
#pragma unroll
    for (int p = 0; p < 4; ++p) {
        cnt0[p] = min(end[p] - beg[p], 16);
        my[p] = (sub < cnt0[p]) ? esrc[beg[p] + sub] : 0;
    }
#pragma unroll
    for (int p = 0; p < 4; ++p)
        wd[p] = (sub < cnt0[p]) ? dis[my[p]] : 0.0f;

    // ---- accumulate per quad (metadata already in flight) ----
#pragma unroll
    for (int p = 0; p < 4; ++p) {
        float acc[8];
#pragma unroll
        for (int e = 0; e < 4; ++e) {  // self term: dis_i * h[i]
            acc[2 * e] = di[p] * bf_lo(selfrow[p][e]);
            acc[2 * e + 1] = di[p] * bf_hi(selfrow[p][e]);
        }
        if (cnt0[p] > 0) accum_chunk_w(hs, my[p], wd[p], cnt0[p], grp, sub, acc);
        // rare chunks beyond 16 edges
        for (int j = beg[p] + 16; j < end[p]; j += 16) {
            const int cnt = min(end[p] - j, 16);
            const int me = (sub < cnt) ? esrc[j + sub] : 0;
            const float mw = (sub < cnt) ? dis[me] : 0.0f;
            accum_chunk_w(hs, me, mw, cnt, grp, sub, acc);
        }

        float o[8];
        o[0] = di[p] * acc[0] + bv0.x; o[1] = di[p] * acc[1] + bv0.y;
        o[2] = di[p] * acc[2] + bv0.z; o[3] = di[p] * acc[3] + bv0.w;
        o[4] = di[p] * acc[4] + bv1.x; o[5] = di[p] * acc[5] + bv1.y;
        o[6] = di[p] * acc[6] + bv1.z; o[7] = di[p] * acc[7] + bv1.w;

        u32x4 w;  // ReLU + bf16 pack
#pragma unroll
        for (int e = 0; e < 4; ++e)
            w[e] = (unsigned)f2bf(fmaxf(o[2 * e], 0.0f)) |
                   ((unsigned)f2bf(fmaxf(o[2 * e + 1], 0.0f)) << 16);
        const int lrow = wv * 16 + p * 4 + grp;
        const int waddr = lrow * 128 + ((sub * 8) ^ ((lrow & 7) << 3));
        *reinterpret_cast<u32x4*>(&At[waddr]) = w;
    }
    __syncthreads();

    // ---- GEMM phase ----
    bf16x8 a[4];
#pragma unroll
    for (int kk = 0; kk < 4; ++kk) {
        const int raddr = (wv * 16 + col16) * 128 +
                          ((kk * 32 + kgrp * 8) ^ ((col16 & 7) << 3));
        a[kk] = *reinterpret_cast<const bf16x8*>(&At[raddr]);
    }

    const int node = st * 32 + wv * 16 + col16;
    const float dn = (node < n) ? dis[node] : 0.0f;
    unsigned short* op = outbf + (size_t)node * D + kgrp * 4;

#pragma unroll
    for (int h = 0; h < 2; ++h) {
        bf16x8 bw[4][4];
#pragma unroll
        for (int c2 = 0; c2 < 4; ++c2)
#pragma unroll
            for (int kk = 0; kk < 4; ++kk)
                bw[c2][kk] = *reinterpret_cast<const bf16x8*>(
                        wp + (size_t)(((h * 4 + c2) * 4 + kk) * 64 + lane) * 8);

        f32x4 acc2[4];
#pragma unroll
        for (int c2 = 0; c2 < 4; ++c2) acc2[c2] = (f32x4){0.f, 0.f, 0.f, 0.f};
#pragma unroll
        for (int kk = 0; kk < 4; ++kk)
#pragma unroll
            for (int c2 = 0; c2 < 4; ++c2)
                acc2[c2] = __builtin_amdgcn_mfma_f32_16x16x32_bf16(bw[c2][kk], a[kk], acc2[c2], 0, 0, 0);

        if (node < n) {
#pragma unroll
            for (int c2 = 0; c2 < 4; ++c2) {
                uint2 w;  // hs2 pre-scaled by dis (gather_agg stays unweighted)
                w.x = (unsigned)f2bf(dn * acc2[c2][0]) | ((unsigned)f2bf(dn * acc2[c2][1]) << 16);
                w.y = (unsigned)f2bf(dn * acc2[c2][2]) | ((unsigned)f2bf(dn * acc2[c2][3]) << 16);
                *reinterpret_cast<uint2*>(op + (h * 4 + c2) * 16) = w;
            }
        }
    }
}

// ---------------- standalone gather-aggregate (layer 2 output, f32) ----------------
__global__ __launch_bounds__(256) void k_gather_agg(const unsigned short* __restrict__ hs,
                                                    const int* __restrict__ starts,
                                                    const int* __restrict__ esrc,
                                                    const float* __restrict__ dis,
                                                    const float* __restrict__ b,
                                                    float* __restrict__ outv, int n) {
    const int lane = threadIdx.x & 63;
    const int wv = threadIdx.x >> 6;
    const int grp = lane >> 4;
    const int sub = lane & 15;
    const int i = (blockIdx.x * 4 + wv) * 4 + grp;
    const bool active = (i < n);
    const int ic = active ? i : (n - 1);

    const float di = dis[ic];
    const int beg = starts[ic];
    const int end = starts[ic + 1];

    float acc[8];
    {   // self-loop row
        const u32x4 u = *reinterpret_cast<const u32x4*>(hs + (size_t)ic * D + sub * 8);
#pragma unroll
        for (int e = 0; e < 4; ++e) {
            acc[2 * e] = bf_lo(u[e]);
            acc[2 * e + 1] = bf_hi(u[e]);
        }
    }
    for (int j = beg; j < end; j += 16) {
        const int cnt = min(end - j, 16);
        const int me = (sub < cnt) ? esrc[j + sub] : 0;
        accum_chunk(hs, me, cnt, grp, sub, acc);
    }

    if (!active) return;

    const float4 bv0 = reinterpret_cast<const float4*>(b)[sub * 2 + 0];
    const float4 bv1 = reinterpret_cast<const float4*>(b)[sub * 2 + 1];
    float4* op = reinterpret_cast<float4*>(outv + (size_t)i * D + sub * 8);
    op[0] = make_float4(di * acc[0] + bv0.x, di * acc[1] + bv0.y,
                        di * acc[2] + bv0.z, di * acc[3] + bv0.w);
    op[1] = make_float4(di * acc[4] + bv1.x, di * acc[5] + bv1.y,
                        di * acc[6] + bv1.z, di * acc[7] + bv1.w);
}

extern "C" void kernel_launch(void* const* d_in, const int* in_sizes, int n_in,
                              void* d_out, int out_size, void* d_ws, size_t ws_size,
                              hipStream_t stream) {
    const float* x  = (const float*)d_in[0];
    const int*   ei = (const int*)d_in[1];   // [2, E]
    const float* W1 = (const float*)d_in[2];
    const float* b1 = (const float*)d_in[3];
    const float* W2 = (const float*)d_in[4];
    const float* b2 = (const float*)d_in[5];
    float* out = (float*)d_out;

    const int n  = in_sizes[0] / D;
    const int nE = in_sizes[1] / 2;
    const int* src = ei;
    const int* dst = ei + nE;

    char* ws = (char*)d_ws;
    float*          dis    = (float*)(ws);                  // n f32
    int*            counts = (int*)(ws + (1ull  << 19));    // n i32
    int*            starts = (int*)(ws + (2ull  << 19));    // n+1 i32
    int*            esrc   = (int*)(ws + (4ull  << 19));    // nE i32 (2..4.4M)
    int*            bsum   = (int*)(ws + (6ull  << 20));    // <=128 i32
    unsigned short* hs_bf  = (unsigned short*)(ws + (8ull  << 20));  // n*128 bf16
    int*            rank   = (int*)(ws + (34ull << 20));    // nE i32
    unsigned short* wp     = (unsigned short*)(ws + (37ull << 20));  // 64KB (both layers)
    unsigned short* hs2_bf = (unsigned short*)(ws + (40ull << 20));  // n*128 bf16

    unsigned short* wp1 = wp;
    unsigned short* wp2 = wp + 2048 * 8;

    const int B = 256;
    const int gn = (n + B - 1) / B;
    const int ge4 = (nE + B * 4 - 1) / (B * 4);
    const int nB = (n + 1023) / 1024;  // <=128 for n<=131072

    const int nst = (n + 63) / 64;
    const int nst32 = (n + 31) / 32;
    const int agg_grid = (n + 15) / 16;

    // W pre-pack (both layers) + counts zero, one launch
    k_pack_zero<<<16 + gn, B, 0, stream>>>(W1, W2, wp, counts, n);

    // ---- FUSED: hist_rank (blocks < ge4) || layer-1 GEMM unscaled (blocks >= ge4) ----
    k_hist_gemm<<<ge4 + nst, B, 0, stream>>>(dst, counts, rank, nE, ge4,
                                             x, wp1, hs_bf, n);
    // CSR finish
    k_scan_part<<<nB, B, 0, stream>>>(counts, bsum, dis, n);
    k_scan_final<<<nB, B, 0, stream>>>(counts, bsum, starts, n, nB);
    k_scatter_nr<<<ge4, B, 0, stream>>>(src, dst, rank, starts, esrc, nE);

    // ---- FUSED: agg1(+b1,ReLU, per-edge dis) -> @W2 -> hs2 (pre-scaled) ----
    k_gather_gemm<<<nst32, 128, 0, stream>>>(hs_bf, starts, esrc, dis, b1, wp2, hs2_bf, n);
    // ---- layer 2 aggregation -> f32 output ----
    k_gather_agg<<<agg_grid, B, 0, stream>>>(hs2_bf, starts, esrc, dis, b2, out, n);
}

// Round 17
// 141.103 us; speedup vs baseline: 1.0964x; 1.0027x over previous
//
#include <hip/hip_runtime.h>

#define D 128

typedef __attribute__((ext_vector_type(8))) short bf16x8;
typedef __attribute__((ext_vector_type(4))) float f32x4;
typedef __attribute__((ext_vector_type(4))) unsigned u32x4;

__device__ inline unsigned short f2bf(float f) {  // RNE fp32->bf16
    unsigned u = __builtin_bit_cast(unsigned, f);
    u += 0x7FFFu + ((u >> 16) & 1u);
    return (unsigned short)(u >> 16);
}
__device__ inline float bf_lo(unsigned u) { return __builtin_bit_cast(float, u << 16); }
__device__ inline float bf_hi(unsigned u) { return __builtin_bit_cast(float, u & 0xFFFF0000u); }

// ---------------- W pre-pack (both layers) + counts zero, one launch ----------------
__global__ __launch_bounds__(256) void k_pack_zero(const float* __restrict__ W1,
                                                   const float* __restrict__ W2,
                                                   unsigned short* __restrict__ wp,
                                                   int* __restrict__ counts, int n) {
    if (blockIdx.x < 16) {
        const int t = blockIdx.x * 256 + threadIdx.x;  // 0..4095
        const float* W = (t < 2048) ? W1 : W2;
        const int tt = t & 2047;
        const int lane = tt & 63;
        const int frag = tt >> 6;  // 0..31
        const int ct = frag >> 2;
        const int kk = frag & 3;
        const int col16 = lane & 15;
        const int kgrp = lane >> 4;
        bf16x8 d;
#pragma unroll
        for (int e = 0; e < 8; ++e)
            d[e] = (short)f2bf(W[(kk * 32 + kgrp * 8 + e) * D + ct * 16 + col16]);
        *reinterpret_cast<bf16x8*>(wp + (size_t)t * 8) = d;
    } else {
        const int i = (blockIdx.x - 16) * 256 + threadIdx.x;
        if (i < n) counts[i] = 0;
    }
}

// ---------------- FUSED hist_rank + layer-1 GEMM (independent work, one launch) ----
// Blocks [0, nsc): histogram + per-edge rank (atomicAdd return value).
// Blocks [nsc, nsc+nst): 64-row MFMA tile of h = x @ W1 (UNSCALED - no dis dep).
// R16: GEMM role holds NOTHING across the ct loop - a[kk] is re-read from LDS
// inside each iteration. Persistent state ~8 regs, so even the allocator's
// aggressive low-VGPR target (28, triggered by the hist atomics) fits with
// ZERO scratch (R14/R15: 46MB WRITE_SIZE from spilling a[]/pf[] across the loop).
__global__ __launch_bounds__(256, 2) void k_hist_gemm(const int* __restrict__ dst,
                                                      int* __restrict__ counts,
                                                      int* __restrict__ rank, int nE, int nsc,
                                                      const float* __restrict__ X,
                                                      const unsigned short* __restrict__ wp,
                                                      unsigned short* __restrict__ outbf,
                                                      int n) {
    __shared__ __align__(16) unsigned short At[64 * 128];  // 16KB, swizzled
    if (blockIdx.x < nsc) {
        // ---------- histogram role ----------
        int e4 = (blockIdx.x * blockDim.x + threadIdx.x) * 4;
        if (e4 + 4 <= nE) {
            const int4 d = *reinterpret_cast<const int4*>(dst + e4);
            int4 r;
            r.x = atomicAdd(&counts[d.x], 1);
            r.y = atomicAdd(&counts[d.y], 1);
            r.z = atomicAdd(&counts[d.z], 1);
            r.w = atomicAdd(&counts[d.w], 1);
            *reinterpret_cast<int4*>(rank + e4) = r;
        } else {
            for (int e = e4; e < nE; ++e) rank[e] = atomicAdd(&counts[dst[e]], 1);
        }
        return;
    }
    // ---------- GEMM role ----------
    const int st = blockIdx.x - nsc;
    const int tid = threadIdx.x;
    const int lane = tid & 63;
    const int wv = tid >> 6;
    const int col16 = lane & 15;
    const int kgrp = lane >> 4;

    // stage X tile -> bf16 swizzled LDS (pf transient: dead before barrier)
#pragma unroll
    for (int c = 0; c < 4; ++c) {
        const int idx = c * 2048 + tid * 8;
        const int row = idx >> 7;
        const int col = idx & 127;
        int grow = st * 64 + row;
        if (grow >= n) grow = n - 1;
        const float4* p = reinterpret_cast<const float4*>(X + (size_t)grow * D + col);
        const float4 f0 = p[0], f1 = p[1];
        float v[8] = {f0.x, f0.y, f0.z, f0.w, f1.x, f1.y, f1.z, f1.w};
        bf16x8 d;
#pragma unroll
        for (int e = 0; e < 8; ++e) d[e] = (short)f2bf(v[e]);
        const int waddr = row * 128 + (col ^ ((row & 7) << 3));
        *reinterpret_cast<bf16x8*>(&At[waddr]) = d;
    }
    __syncthreads();

    const int node = st * 64 + wv * 16 + col16;
    unsigned short* op = outbf + (size_t)node * D + kgrp * 4;
    const int abase = (wv * 16 + col16) * 128;
    const int axor = (col16 & 7) << 3;

    // ---- per-ct streamed epilogue: re-read a[kk] from LDS each iteration ----
#pragma unroll 1
    for (int ct = 0; ct < 8; ++ct) {
        bf16x8 bw0 = *reinterpret_cast<const bf16x8*>(wp + (size_t)((ct * 4 + 0) * 64 + lane) * 8);
        bf16x8 bw1 = *reinterpret_cast<const bf16x8*>(wp + (size_t)((ct * 4 + 1) * 64 + lane) * 8);
        bf16x8 bw2 = *reinterpret_cast<const bf16x8*>(wp + (size_t)((ct * 4 + 2) * 64 + lane) * 8);
        bf16x8 bw3 = *reinterpret_cast<const bf16x8*>(wp + (size_t)((ct * 4 + 3) * 64 + lane) * 8);

        f32x4 acc = (f32x4){0.f, 0.f, 0.f, 0.f};
        bf16x8 a;
        a = *reinterpret_cast<const bf16x8*>(&At[abase + ((0 * 32 + kgrp * 8) ^ axor)]);
        acc = __builtin_amdgcn_mfma_f32_16x16x32_bf16(bw0, a, acc, 0, 0, 0);
        a = *reinterpret_cast<const bf16x8*>(&At[abase + ((1 * 32 + kgrp * 8) ^ axor)]);
        acc = __builtin_amdgcn_mfma_f32_16x16x32_bf16(bw1, a, acc, 0, 0, 0);
        a = *reinterpret_cast<const bf16x8*>(&At[abase + ((2 * 32 + kgrp * 8) ^ axor)]);
        acc = __builtin_amdgcn_mfma_f32_16x16x32_bf16(bw2, a, acc, 0, 0, 0);
        a = *reinterpret_cast<const bf16x8*>(&At[abase + ((3 * 32 + kgrp * 8) ^ axor)]);
        acc = __builtin_amdgcn_mfma_f32_16x16x32_bf16(bw3, a, acc, 0, 0, 0);

        if (node < n) {
            uint2 w;  // UNSCALED epilogue (dis applied at gather time)
            w.x = (unsigned)f2bf(acc[0]) | ((unsigned)f2bf(acc[1]) << 16);
            w.y = (unsigned)f2bf(acc[2]) | ((unsigned)f2bf(acc[3]) << 16);
            *reinterpret_cast<uint2*>(op + ct * 16) = w;
        }
    }
}

// Pass 1: per-block (1024-element tile) sums; fused dis = rsqrt(counts+1).
__global__ __launch_bounds__(256) void k_scan_part(const int* __restrict__ counts,
                                                   int* __restrict__ bsum,
                                                   float* __restrict__ dis, int n) {
    const int t = threadIdx.x;
    const int base = blockIdx.x * 1024 + t * 4;
    int4 c = make_int4(0, 0, 0, 0);
    if (base + 4 <= n) {
        c = *reinterpret_cast<const int4*>(counts + base);
        float4 dv;
        dv.x = rsqrtf((float)(c.x + 1));
        dv.y = rsqrtf((float)(c.y + 1));
        dv.z = rsqrtf((float)(c.z + 1));
        dv.w = rsqrtf((float)(c.w + 1));
        *reinterpret_cast<float4*>(dis + base) = dv;
    } else if (base < n) {
        int cc[4] = {0, 0, 0, 0};
        for (int k = 0; k < 4; ++k)
            if (base + k < n) {
                cc[k] = counts[base + k];
                dis[base + k] = rsqrtf((float)(cc[k] + 1));
            }
        c.x = cc[0]; c.y = cc[1]; c.z = cc[2]; c.w = cc[3];
    }
    __shared__ int red[256];
    red[t] = c.x + c.y + c.z + c.w;
    __syncthreads();
    for (int off = 128; off > 0; off >>= 1) {
        if (t < off) red[t] += red[t + off];
        __syncthreads();
    }
    if (t == 0) bsum[blockIdx.x] = red[0];
}

// Pass 2: scan block sums in LDS, local-scan tile, write starts.
__global__ __launch_bounds__(256) void k_scan_final(const int* __restrict__ counts,
                                                    const int* __restrict__ bsum,
                                                    int* __restrict__ starts, int n, int nB) {
    __shared__ int sb[128];
    __shared__ int ts[256];
    const int t = threadIdx.x;
    const int b = blockIdx.x;

    if (t < 128) sb[t] = (t < nB) ? bsum[t] : 0;
    __syncthreads();
    for (int off = 1; off < 128; off <<= 1) {
        int add = (t < 128 && t >= off) ? sb[t - off] : 0;
        __syncthreads();
        if (t < 128) sb[t] += add;
        __syncthreads();
    }
    const int block_off = (b > 0) ? sb[b - 1] : 0;

    const int base = b * 1024 + t * 4;
    int4 c = make_int4(0, 0, 0, 0);
    if (base + 4 <= n) {
        c = *reinterpret_cast<const int4*>(counts + base);
    } else if (base < n) {
        if (base + 0 < n) c.x = counts[base + 0];
        if (base + 1 < n) c.y = counts[base + 1];
        if (base + 2 < n) c.z = counts[base + 2];
    }
    const int s = c.x + c.y + c.z + c.w;
    ts[t] = s;
    __syncthreads();
    for (int off = 1; off < 256; off <<= 1) {
        int add = (t >= off) ? ts[t - off] : 0;
        __syncthreads();
        ts[t] += add;
        __syncthreads();
    }
    int excl = block_off + ts[t] - s;

    int4 w;
    w.x = excl;
    w.y = w.x + c.x;
    w.z = w.y + c.y;
    w.w = w.z + c.z;
    if (base + 4 <= n) {
        *reinterpret_cast<int4*>(starts + base) = w;
    } else if (base < n) {
        if (base + 0 < n) starts[base + 0] = w.x;
        if (base + 1 < n) starts[base + 1] = w.y;
        if (base + 2 < n) starts[base + 2] = w.z;
    }
    if (b == 0 && t == 0) starts[n] = sb[nB - 1];  // = nE
}

// Atomic-free scatter: position = starts[dst] + precomputed rank.
__global__ void k_scatter_nr(const int* __restrict__ src, const int* __restrict__ dst,
                             const int* __restrict__ rank, const int* __restrict__ starts,
                             int* __restrict__ esrc, int nE) {
    int e4 = (blockIdx.x * blockDim.x + threadIdx.x) * 4;
    if (e4 + 4 <= nE) {
        const int4 s = *reinterpret_cast<const int4*>(src + e4);
        const int4 d = *reinterpret_cast<const int4*>(dst + e4);
        const int4 r = *reinterpret_cast<const int4*>(rank + e4);
        esrc[starts[d.x] + r.x] = s.x;
        esrc[starts[d.y] + r.y] = s.y;
        esrc[starts[d.z] + r.z] = s.z;
        esrc[starts[d.w] + r.w] = s.w;
    } else {
        for (int e = e4; e < nE; ++e)
            esrc[starts[dst[e]] + rank[e]] = src[e];
    }
}

// ---------------- gather chunk cores: 8-deep pipelined row accumulate ----------------
// Unweighted (pre-scaled rows):
__device__ __forceinline__ void accum_chunk(const unsigned short* __restrict__ hs,
                                            int myedge, int cnt, int grp, int sub,
                                            float acc[8]) {
    auto row16 = [&](int s) -> u32x4 {
        return *reinterpret_cast<const u32x4*>(hs + (size_t)s * D + sub * 8);
    };
    for (int k = 0; k < cnt; k += 8) {
        u32x4 u[8];
#pragma unroll
        for (int q = 0; q < 8; ++q) {
            const int tq = min(k + q, cnt - 1);  // clamp: dupes hit L1
            const int s = __shfl(myedge, (grp << 4) | tq);
            u[q] = row16(s);
        }
        const int rem = cnt - k;
#pragma unroll
        for (int q = 0; q < 8; ++q) {
            if (q < rem) {
#pragma unroll
                for (int e = 0; e < 4; ++e) {
                    acc[2 * e] += bf_lo(u[q][e]);
                    acc[2 * e + 1] += bf_hi(u[q][e]);
                }
            }
        }
    }
}

// Weighted (unscaled rows; weight dis[src] shfl'd alongside the index):
__device__ __forceinline__ void accum_chunk_w(const unsigned short* __restrict__ hs,
                                              int myedge, float myw, int cnt, int grp, int sub,
                                              float acc[8]) {
    auto row16 = [&](int s) -> u32x4 {
        return *reinterpret_cast<const u32x4*>(hs + (size_t)s * D + sub * 8);
    };
    for (int k = 0; k < cnt; k += 8) {
        u32x4 u[8];
        float w[8];
#pragma unroll
        for (int q = 0; q < 8; ++q) {
            const int tq = min(k + q, cnt - 1);
            const int sl = (grp << 4) | tq;
            const int s = __shfl(myedge, sl);
            w[q] = __shfl(myw, sl);
            u[q] = row16(s);
        }
        const int rem = cnt - k;
#pragma unroll
        for (int q = 0; q < 8; ++q) {
            if (q < rem) {
#pragma unroll
                for (int e = 0; e < 4; ++e) {
                    acc[2 * e] += w[q] * bf_lo(u[q][e]);
                    acc[2 * e + 1] += w[q] * bf_hi(u[q][e]);
                }
            }
        }
    }
}

// ---------------- FUSED gather + GEMM (layer 1 agg + layer 2 matmul) ----------------
// h is UNSCALED; dis[src] gathered per edge (4B, shfl-broadcast) and applied
// via FMA. agg = dis_i * (sum dis_s*h[s] + dis_i*h[i]) + b. 128 thr / 32-row tiles.
__global__ __launch_bounds__(128, 4) void k_gather_gemm(const unsigned short* __restrict__ hs,
                                                        const int* __restrict__ starts,
                                                        const int* __restrict__ esrc,
                                                        const float* __restrict__ dis,
                                                        const float* __restrict__ bias,
                                                        const unsigned short* __restrict__ wp,
                                                        unsigned short* __restrict__ outbf,
                                                        int n) {
    __shared__ __align__(16) unsigned short At[32 * 128];  // 8KB, swizzled
    const int tid = threadIdx.x;
    const int lane = tid & 63;
    const int wv = tid >> 6;     // 0..1
    const int col16 = lane & 15;
    const int kgrp = lane >> 4;
    const int grp = lane >> 4;   // node within 4-node quad
    const int sub = lane & 15;   // lane within node
    const int st = blockIdx.x;

    const float4 bv0 = reinterpret_cast<const float4*>(bias)[sub * 2 + 0];
    const float4 bv1 = reinterpret_cast<const float4*>(bias)[sub * 2 + 1];

    // ---- metadata for all 4 quads: independent loads, all in flight together ----
    int ic[4], beg[4], end[4], cnt0[4], my[4];
    float di[4], wd[4];
    u32x4 selfrow[4];
#pragma unroll
    for (int p = 0; p < 4; ++p) {
        const int i = st * 32 + wv * 16 + p * 4 + grp;
        ic[p] = (i < n) ? i : (n - 1);
    }
#pragma unroll
    for (int p = 0; p < 4; ++p) {
        beg[p] = starts[ic[p]];
        end[p] = starts[ic[p] + 1];
        di[p] = dis[ic[p]];
        selfrow[p] = *reinterpret_cast<const u32x4*>(hs + (size_t)ic[p] * D + sub * 8);
    }
#pragma unroll
    for (int p = 0; p < 4; ++p) {
        cnt0[p] = min(end[p] - beg[p], 16);
        my[p] = (sub < cnt0[p]) ? esrc[beg[p] + sub] : 0;
    }
#pragma unroll
    for (int p = 0; p < 4; ++p)
        wd[p] = (sub < cnt0[p]) ? dis[my[p]] : 0.0f;

    // ---- accumulate per quad (metadata already in flight) ----
#pragma unroll
    for (int p = 0; p < 4; ++p) {
        float acc[8];
#pragma unroll
        for (int e = 0; e < 4; ++e) {  // self term: dis_i * h[i]
            acc[2 * e] = di[p] * bf_lo(selfrow[p][e]);
            acc[2 * e + 1] = di[p] * bf_hi(selfrow[p][e]);
        }
        if (cnt0[p] > 0) accum_chunk_w(hs, my[p], wd[p], cnt0[p], grp, sub, acc);
        // rare chunks beyond 16 edges
        for (int j = beg[p] + 16; j < end[p]; j += 16) {
            const int cnt = min(end[p] - j, 16);
            const int me = (sub < cnt) ? esrc[j + sub] : 0;
            const float mw = (sub < cnt) ? dis[me] : 0.0f;
            accum_chunk_w(hs, me, mw, cnt, grp, sub, acc);
        }

        float o[8];
        o[0] = di[p] * acc[0] + bv0.x; o[1] = di[p] * acc[1] + bv0.y;
        o[2] = di[p] * acc[2] + bv0.z; o[3] = di[p] * acc[3] + bv0.w;
        o[4] = di[p] * acc[4] + bv1.x; o[5] = di[p] * acc[5] + bv1.y;
        o[6] = di[p] * acc[6] + bv1.z; o[7] = di[p] * acc[7] + bv1.w;

        u32x4 w;  // ReLU + bf16 pack
#pragma unroll
        for (int e = 0; e < 4; ++e)
            w[e] = (unsigned)f2bf(fmaxf(o[2 * e], 0.0f)) |
                   ((unsigned)f2bf(fmaxf(o[2 * e + 1], 0.0f)) << 16);
        const int lrow = wv * 16 + p * 4 + grp;
        const int waddr = lrow * 128 + ((sub * 8) ^ ((lrow & 7) << 3));
        *reinterpret_cast<u32x4*>(&At[waddr]) = w;
    }
    __syncthreads();

    // ---- GEMM phase ----
    bf16x8 a[4];
#pragma unroll
    for (int kk = 0; kk < 4; ++kk) {
        const int raddr = (wv * 16 + col16) * 128 +
                          ((kk * 32 + kgrp * 8) ^ ((col16 & 7) << 3));
        a[kk] = *reinterpret_cast<const bf16x8*>(&At[raddr]);
    }

    const int node = st * 32 + wv * 16 + col16;
    const float dn = (node < n) ? dis[node] : 0.0f;
    unsigned short* op = outbf + (size_t)node * D + kgrp * 4;

#pragma unroll
    for (int h = 0; h < 2; ++h) {
        bf16x8 bw[4][4];
#pragma unroll
        for (int c2 = 0; c2 < 4; ++c2)
#pragma unroll
            for (int kk = 0; kk < 4; ++kk)
                bw[c2][kk] = *reinterpret_cast<const bf16x8*>(
                        wp + (size_t)(((h * 4 + c2) * 4 + kk) * 64 + lane) * 8);

        f32x4 acc2[4];
#pragma unroll
        for (int c2 = 0; c2 < 4; ++c2) acc2[c2] = (f32x4){0.f, 0.f, 0.f, 0.f};
#pragma unroll
        for (int kk = 0; kk < 4; ++kk)
#pragma unroll
            for (int c2 = 0; c2 < 4; ++c2)
                acc2[c2] = __builtin_amdgcn_mfma_f32_16x16x32_bf16(bw[c2][kk], a[kk], acc2[c2], 0, 0, 0);

        if (node < n) {
#pragma unroll
            for (int c2 = 0; c2 < 4; ++c2) {
                uint2 w;  // hs2 pre-scaled by dis (gather_agg stays unweighted)
                w.x = (unsigned)f2bf(dn * acc2[c2][0]) | ((unsigned)f2bf(dn * acc2[c2][1]) << 16);
                w.y = (unsigned)f2bf(dn * acc2[c2][2]) | ((unsigned)f2bf(dn * acc2[c2][3]) << 16);
                *reinterpret_cast<uint2*>(op + (h * 4 + c2) * 16) = w;
            }
        }
    }
}

// ---------------- standalone gather-aggregate (layer 2 output, f32) ----------------
__global__ __launch_bounds__(256) void k_gather_agg(const unsigned short* __restrict__ hs,
                                                    const int* __restrict__ starts,
                                                    const int* __restrict__ esrc,
                                                    const float* __restrict__ dis,
                                                    const float* __restrict__ b,
                                                    float* __restrict__ outv, int n) {
    const int lane = threadIdx.x & 63;
    const int wv = threadIdx.x >> 6;
    const int grp = lane >> 4;
    const int sub = lane & 15;
    const int i = (blockIdx.x * 4 + wv) * 4 + grp;
    const bool active = (i < n);
    const int ic = active ? i : (n - 1);

    const float di = dis[ic];
    const int beg = starts[ic];
    const int end = starts[ic + 1];

    float acc[8];
    {   // self-loop row
        const u32x4 u = *reinterpret_cast<const u32x4*>(hs + (size_t)ic * D + sub * 8);
#pragma unroll
        for (int e = 0; e < 4; ++e) {
            acc[2 * e] = bf_lo(u[e]);
            acc[2 * e + 1] = bf_hi(u[e]);
        }
    }
    for (int j = beg; j < end; j += 16) {
        const int cnt = min(end - j, 16);
        const int me = (sub < cnt) ? esrc[j + sub] : 0;
        accum_chunk(hs, me, cnt, grp, sub, acc);
    }

    if (!active) return;

    const float4 bv0 = reinterpret_cast<const float4*>(b)[sub * 2 + 0];
    const float4 bv1 = reinterpret_cast<const float4*>(b)[sub * 2 + 1];
    float4* op = reinterpret_cast<float4*>(outv + (size_t)i * D + sub * 8);
    op[0] = make_float4(di * acc[0] + bv0.x, di * acc[1] + bv0.y,
                        di * acc[2] + bv0.z, di * acc[3] + bv0.w);
    op[1] = make_float4(di * acc[4] + bv1.x, di * acc[5] + bv1.y,
                        di * acc[6] + bv1.z, di * acc[7] + bv1.w);
}

extern "C" void kernel_launch(void* const* d_in, const int* in_sizes, int n_in,
                              void* d_out, int out_size, void* d_ws, size_t ws_size,
                              hipStream_t stream) {
    const float* x  = (const float*)d_in[0];
    const int*   ei = (const int*)d_in[1];   // [2, E]
    const float* W1 = (const float*)d_in[2];
    const float* b1 = (const float*)d_in[3];
    const float* W2 = (const float*)d_in[4];
    const float* b2 = (const float*)d_in[5];
    float* out = (float*)d_out;

    const int n  = in_sizes[0] / D;
    const int nE = in_sizes[1] / 2;
    const int* src = ei;
    const int* dst = ei + nE;

    char* ws = (char*)d_ws;
    float*          dis    = (float*)(ws);                  // n f32
    int*            counts = (int*)(ws + (1ull  << 19));    // n i32
    int*            starts = (int*)(ws + (2ull  << 19));    // n+1 i32
    int*            esrc   = (int*)(ws + (4ull  << 19));    // nE i32 (2..4.4M)
    int*            bsum   = (int*)(ws + (6ull  << 20));    // <=128 i32
    unsigned short* hs_bf  = (unsigned short*)(ws + (8ull  << 20));  // n*128 bf16
    int*            rank   = (int*)(ws + (34ull << 20));    // nE i32
    unsigned short* wp     = (unsigned short*)(ws + (37ull << 20));  // 64KB (both layers)
    unsigned short* hs2_bf = (unsigned short*)(ws + (40ull << 20));  // n*128 bf16

    unsigned short* wp1 = wp;
    unsigned short* wp2 = wp + 2048 * 8;

    const int B = 256;
    const int gn = (n + B - 1) / B;
    const int ge4 = (nE + B * 4 - 1) / (B * 4);
    const int nB = (n + 1023) / 1024;  // <=128 for n<=131072

    const int nst = (n + 63) / 64;
    const int nst32 = (n + 31) / 32;
    const int agg_grid = (n + 15) / 16;

    // W pre-pack (both layers) + counts zero, one launch
    k_pack_zero<<<16 + gn, B, 0, stream>>>(W1, W2, wp, counts, n);

    // ---- FUSED: hist_rank (blocks < ge4) || layer-1 GEMM unscaled (blocks >= ge4) ----
    k_hist_gemm<<<ge4 + nst, B, 0, stream>>>(dst, counts, rank, nE, ge4,
                                             x, wp1, hs_bf, n);
    // CSR finish
    k_scan_part<<<nB, B, 0, stream>>>(counts, bsum, dis, n);
    k_scan_final<<<nB, B, 0, stream>>>(counts, bsum, starts, n, nB);
    k_scatter_nr<<<ge4, B, 0, stream>>>(src, dst, rank, starts, esrc, nE);

    // ---- FUSED: agg1(+b1,ReLU, per-edge dis) -> @W2 -> hs2 (pre-scaled) ----
    k_gather_gemm<<<nst32, 128, 0, stream>>>(hs_bf, starts, esrc, dis, b1, wp2, hs2_bf, n);
    // ---- layer 2 aggregation -> f32 output ----
    k_gather_agg<<<agg_grid, B, 0, stream>>>(hs2_bf, starts, esrc, dis, b2, out, n);
}